// Round 1
// baseline (5924.097 us; speedup 1.0000x reference)
//
#include <hip/hip_runtime.h>

#define Bz 8
#define Tz 8192
#define Cz 256
#define Hz 8
#define Gz 64
#define Dz 32

// ---------------- GEMM, 128x128 block tile, 8x8 micro-tile: Y = X @ W + bias ----------------
__global__ __launch_bounds__(256) void gemm128(
    const float* __restrict__ X, const float* __restrict__ W,
    const float* __restrict__ bias, float* __restrict__ Y) {
  __shared__ __align__(16) float As[16][132];  // [k][row] transposed
  __shared__ __align__(16) float Bs[16][132];  // [k][col]
  const int tid = threadIdx.x;
  const size_t m0 = (size_t)blockIdx.x * 128;
  const int n0 = blockIdx.y * 128;
  const int tx = tid & 15, ty = tid >> 4;
  const int r0 = ty * 8, c0 = tx * 8;
  float acc[8][8] = {};
  for (int kt = 0; kt < Cz; kt += 16) {
    __syncthreads();
#pragma unroll
    for (int u = 0; u < 2; ++u) {
      int idx = tid + u * 256;          // 512 float4 of A tile
      int row = idx >> 2, kq = idx & 3;
      float4 v = *(const float4*)&X[(m0 + row) * Cz + kt + kq * 4];
      As[kq * 4 + 0][row] = v.x;
      As[kq * 4 + 1][row] = v.y;
      As[kq * 4 + 2][row] = v.z;
      As[kq * 4 + 3][row] = v.w;
    }
#pragma unroll
    for (int u = 0; u < 2; ++u) {
      int idx = tid + u * 256;          // 512 float4 of B tile
      int k = idx >> 5, cq = idx & 31;
      *(float4*)&Bs[k][cq * 4] = *(const float4*)&W[(size_t)(kt + k) * Cz + n0 + cq * 4];
    }
    __syncthreads();
#pragma unroll
    for (int kk = 0; kk < 16; ++kk) {
      float4 a0 = *(float4*)&As[kk][r0];
      float4 a1 = *(float4*)&As[kk][r0 + 4];
      float4 b0 = *(float4*)&Bs[kk][c0];
      float4 b1 = *(float4*)&Bs[kk][c0 + 4];
      float av[8] = {a0.x, a0.y, a0.z, a0.w, a1.x, a1.y, a1.z, a1.w};
      float bv[8] = {b0.x, b0.y, b0.z, b0.w, b1.x, b1.y, b1.z, b1.w};
#pragma unroll
      for (int i = 0; i < 8; ++i)
#pragma unroll
        for (int j = 0; j < 8; ++j) acc[i][j] += av[i] * bv[j];
    }
  }
#pragma unroll
  for (int i = 0; i < 8; ++i) {
    size_t row = m0 + r0 + i;
#pragma unroll
    for (int jq = 0; jq < 2; ++jq) {
      float4 o;
      o.x = acc[i][jq * 4 + 0] + bias[n0 + c0 + jq * 4 + 0];
      o.y = acc[i][jq * 4 + 1] + bias[n0 + c0 + jq * 4 + 1];
      o.z = acc[i][jq * 4 + 2] + bias[n0 + c0 + jq * 4 + 2];
      o.w = acc[i][jq * 4 + 3] + bias[n0 + c0 + jq * 4 + 3];
      *(float4*)&Y[row * Cz + n0 + c0 + jq * 4] = o;
    }
  }
}

// ---------------- Fallback: in-place GEMM (32 rows x full 256 cols per block) ----------------
__global__ __launch_bounds__(256) void gemm32ip(
    float* __restrict__ Y, const float* __restrict__ W, const float* __restrict__ bias) {
  __shared__ __align__(16) float As[32][260];  // full K rows staged (in-place safety)
  __shared__ __align__(16) float Bs[16][260];
  const int tid = threadIdx.x;
  const size_t m0 = (size_t)blockIdx.x * 32;
  for (int idx = tid; idx < 32 * 64; idx += 256) {
    int row = idx >> 6, kq = idx & 63;
    *(float4*)&As[row][kq * 4] = *(const float4*)&Y[(m0 + row) * Cz + kq * 4];
  }
  const int tx = tid & 31, ty = tid >> 5;
  const int r0 = ty * 4, c0 = tx * 4;  // cols c0..c0+3 and c0+128..c0+131
  float acc[4][8] = {};
  for (int kt = 0; kt < Cz; kt += 16) {
    __syncthreads();
#pragma unroll
    for (int u = 0; u < 4; ++u) {
      int idx = tid + u * 256;
      int k = idx >> 6, cq = idx & 63;
      *(float4*)&Bs[k][cq * 4] = *(const float4*)&W[(size_t)(kt + k) * Cz + cq * 4];
    }
    __syncthreads();
#pragma unroll
    for (int kk = 0; kk < 16; kk += 4) {
      float4 a4[4];
#pragma unroll
      for (int i = 0; i < 4; ++i) a4[i] = *(float4*)&As[r0 + i][kt + kk];
      float am[4][4];
#pragma unroll
      for (int i = 0; i < 4; ++i) {
        am[i][0] = a4[i].x; am[i][1] = a4[i].y; am[i][2] = a4[i].z; am[i][3] = a4[i].w;
      }
#pragma unroll
      for (int k2 = 0; k2 < 4; ++k2) {
        float4 b0 = *(float4*)&Bs[kk + k2][c0];
        float4 b1 = *(float4*)&Bs[kk + k2][c0 + 128];
#pragma unroll
        for (int i = 0; i < 4; ++i) {
          acc[i][0] += am[i][k2] * b0.x;
          acc[i][1] += am[i][k2] * b0.y;
          acc[i][2] += am[i][k2] * b0.z;
          acc[i][3] += am[i][k2] * b0.w;
          acc[i][4] += am[i][k2] * b1.x;
          acc[i][5] += am[i][k2] * b1.y;
          acc[i][6] += am[i][k2] * b1.z;
          acc[i][7] += am[i][k2] * b1.w;
        }
      }
    }
  }
#pragma unroll
  for (int i = 0; i < 4; ++i) {
    size_t row = m0 + r0 + i;
    float4 o0, o1;
    o0.x = acc[i][0] + bias[c0 + 0];
    o0.y = acc[i][1] + bias[c0 + 1];
    o0.z = acc[i][2] + bias[c0 + 2];
    o0.w = acc[i][3] + bias[c0 + 3];
    o1.x = acc[i][4] + bias[c0 + 128];
    o1.y = acc[i][5] + bias[c0 + 129];
    o1.z = acc[i][6] + bias[c0 + 130];
    o1.w = acc[i][7] + bias[c0 + 131];
    *(float4*)&Y[row * Cz + c0] = o0;
    *(float4*)&Y[row * Cz + c0 + 128] = o1;
  }
}

// ---------------- slice logits -> softmax -> weighted pooling (token accumulation) ----------------
__global__ __launch_bounds__(256) void pool_k(
    const float* __restrict__ tmp, const float* __restrict__ Wslice,
    const float* __restrict__ bslice, const float* __restrict__ temp,
    float* __restrict__ accg, float* __restrict__ normg) {
  __shared__ __align__(16) float Wst[Gz][36];   // [g][d] (transposed W_slice)
  __shared__ __align__(16) float rows[64][36];  // [r][d]
  __shared__ __align__(16) float wsm[64][68];   // [r][g] logits / weights
  __shared__ float bsl[Gz];
  __shared__ float accr[Gz][Dz];
  __shared__ float accn[Gz];
  const int tid = threadIdx.x;
  const int bh = blockIdx.x, b = bh >> 3, h = bh & 7;
  for (int i = tid; i < Gz * Dz; i += 256) {
    int d = i >> 6, g = i & 63;
    Wst[g][d] = Wslice[i];       // W_slice is (D,G) row-major
    ((float*)accr)[i] = 0.f;
  }
  if (tid < Gz) { bsl[tid] = bslice[tid]; accn[tid] = 0.f; }
  const float invt = 1.0f / temp[h];
  const int gg = tid & 15, dq = (tid >> 4) & 3, rh = tid >> 6;
  const int g0 = gg * 4, d0 = dq * 8;
  const int lr = (tid >> 4) * 4, lg = (tid & 15) * 4;
  const int sr = tid >> 2, sq = tid & 3;
  float pacc[4][8] = {};
  float pnorm[4] = {0.f, 0.f, 0.f, 0.f};
  const size_t base = ((size_t)b * Tz + (size_t)blockIdx.y * 512) * Cz + h * Dz;
  for (int sc = 0; sc < 8; ++sc) {
    __syncthreads();
    for (int i = tid; i < 64 * 8; i += 256) {
      int r = i >> 3, kq = i & 7;
      *(float4*)&rows[r][kq * 4] =
          *(const float4*)&tmp[base + (size_t)(sc * 64 + r) * Cz + kq * 4];
    }
    __syncthreads();
    // logits: 4r x 4g per thread
    {
      float lacc[4][4] = {};
#pragma unroll
      for (int k = 0; k < Dz; k += 4) {
        float4 av[4], bv[4];
#pragma unroll
        for (int i = 0; i < 4; ++i) av[i] = *(float4*)&rows[lr + i][k];
#pragma unroll
        for (int j = 0; j < 4; ++j) bv[j] = *(float4*)&Wst[lg + j][k];
#pragma unroll
        for (int i = 0; i < 4; ++i)
#pragma unroll
          for (int j = 0; j < 4; ++j)
            lacc[i][j] += av[i].x * bv[j].x + av[i].y * bv[j].y +
                          av[i].z * bv[j].z + av[i].w * bv[j].w;
      }
#pragma unroll
      for (int i = 0; i < 4; ++i) {
        float4 o;
        o.x = (lacc[i][0] + bsl[lg + 0]) * invt;
        o.y = (lacc[i][1] + bsl[lg + 1]) * invt;
        o.z = (lacc[i][2] + bsl[lg + 2]) * invt;
        o.w = (lacc[i][3] + bsl[lg + 3]) * invt;
        *(float4*)&wsm[lr + i][lg] = o;
      }
    }
    __syncthreads();
    // softmax over g (no max-subtraction: |logit| < ~1.3), 4 threads per row
    {
      float e[16];
      float s = 0.f;
#pragma unroll
      for (int j4 = 0; j4 < 4; ++j4) {
        float4 v = *(float4*)&wsm[sr][sq * 16 + j4 * 4];
        e[j4 * 4 + 0] = __expf(v.x);
        e[j4 * 4 + 1] = __expf(v.y);
        e[j4 * 4 + 2] = __expf(v.z);
        e[j4 * 4 + 3] = __expf(v.w);
        s += e[j4 * 4 + 0] + e[j4 * 4 + 1] + e[j4 * 4 + 2] + e[j4 * 4 + 3];
      }
      s += __shfl_xor(s, 1);
      s += __shfl_xor(s, 2);
      const float inv = 1.0f / s;
#pragma unroll
      for (int j4 = 0; j4 < 4; ++j4) {
        float4 v;
        v.x = e[j4 * 4 + 0] * inv;
        v.y = e[j4 * 4 + 1] * inv;
        v.z = e[j4 * 4 + 2] * inv;
        v.w = e[j4 * 4 + 3] * inv;
        *(float4*)&wsm[sr][sq * 16 + j4 * 4] = v;
      }
    }
    __syncthreads();
    // accumulate: thread owns (4g x 8d), 16 rows slice (rh)
#pragma unroll
    for (int rr = 0; rr < 16; ++rr) {
      const int r = rh * 16 + rr;
      float4 w4 = *(float4*)&wsm[r][g0];
      float4 ra = *(float4*)&rows[r][d0];
      float4 rb = *(float4*)&rows[r][d0 + 4];
      const float wv[4] = {w4.x, w4.y, w4.z, w4.w};
      const float rv[8] = {ra.x, ra.y, ra.z, ra.w, rb.x, rb.y, rb.z, rb.w};
#pragma unroll
      for (int i = 0; i < 4; ++i)
#pragma unroll
        for (int j = 0; j < 8; ++j) pacc[i][j] += wv[i] * rv[j];
      if (dq == 0) {
#pragma unroll
        for (int i = 0; i < 4; ++i) pnorm[i] += wv[i];
      }
    }
  }
  __syncthreads();
#pragma unroll
  for (int i = 0; i < 4; ++i)
#pragma unroll
    for (int j = 0; j < 8; ++j) atomicAdd(&accr[g0 + i][d0 + j], pacc[i][j]);
  if (dq == 0) {
#pragma unroll
    for (int i = 0; i < 4; ++i) atomicAdd(&accn[g0 + i], pnorm[i]);
  }
  __syncthreads();
  for (int i = tid; i < Gz * Dz; i += 256)
    atomicAdd(&accg[(size_t)bh * Gz * Dz + i], ((float*)accr)[i]);
  if (tid < Gz) atomicAdd(&normg[bh * Gz + tid], accn[tid]);
}

// ---------------- tiny per-(b,h) attention over G=64 slice tokens ----------------
__global__ __launch_bounds__(256) void attn_k(
    const float* __restrict__ accg, const float* __restrict__ normg,
    const float* __restrict__ Wq, const float* __restrict__ bq,
    const float* __restrict__ Wk, const float* __restrict__ bk,
    const float* __restrict__ Wv, const float* __restrict__ bv,
    float* __restrict__ osg) {
  __shared__ __align__(16) char pool[50560];
  float(*tok)[36] = (float(*)[36])pool;               // 64x36
  float(*wqs)[36] = (float(*)[36])(pool + 9216);      // 32x36
  float(*wks)[36] = (float(*)[36])(pool + 13824);
  float(*wvs)[36] = (float(*)[36])(pool + 18432);     // ends 23040
  float(*sarr)[68] = (float(*)[68])pool;              // 64x68, aliases tok/wqs/wks (dead then)
  float(*qs)[36] = (float(*)[36])(pool + 23040);
  float(*ks)[36] = (float(*)[36])(pool + 32256);
  float(*vt)[68] = (float(*)[68])(pool + 41472);      // 32x68 (v transposed) ends 50176
  float* bqs = (float*)(pool + 50176);
  float* bks = bqs + 32;
  float* bvs = bks + 32;
  const int tid = threadIdx.x;
  const int bh = blockIdx.x;
  for (int i = tid; i < Gz * Dz; i += 256) {
    int g = i >> 5;
    tok[g][i & 31] = accg[(size_t)bh * 2048 + i] / (normg[bh * 64 + g] + 1e-5f);
  }
  for (int i = tid; i < Dz * Dz; i += 256) {
    int d = i >> 5, j = i & 31;
    wqs[d][j] = Wq[i];
    wks[d][j] = Wk[i];
    wvs[d][j] = Wv[i];
  }
  if (tid < 32) { bqs[tid] = bq[tid]; bks[tid] = bk[tid]; bvs[tid] = bv[tid]; }
  __syncthreads();
  // projections: thread tile 2g x 4j, fused q/k/v
  {
    const int g0 = (tid >> 3) * 2, j0 = (tid & 7) * 4;
    float qa[2][4] = {}, ka[2][4] = {}, va[2][4] = {};
#pragma unroll
    for (int d4 = 0; d4 < Dz; d4 += 4) {
      float4 t0 = *(float4*)&tok[g0][d4];
      float4 t1 = *(float4*)&tok[g0 + 1][d4];
      const float ta[2][4] = {{t0.x, t0.y, t0.z, t0.w}, {t1.x, t1.y, t1.z, t1.w}};
#pragma unroll
      for (int dd = 0; dd < 4; ++dd) {
        float4 wq4 = *(float4*)&wqs[d4 + dd][j0];
        float4 wk4 = *(float4*)&wks[d4 + dd][j0];
        float4 wv4 = *(float4*)&wvs[d4 + dd][j0];
#pragma unroll
        for (int gi = 0; gi < 2; ++gi) {
          qa[gi][0] += ta[gi][dd] * wq4.x;
          qa[gi][1] += ta[gi][dd] * wq4.y;
          qa[gi][2] += ta[gi][dd] * wq4.z;
          qa[gi][3] += ta[gi][dd] * wq4.w;
          ka[gi][0] += ta[gi][dd] * wk4.x;
          ka[gi][1] += ta[gi][dd] * wk4.y;
          ka[gi][2] += ta[gi][dd] * wk4.z;
          ka[gi][3] += ta[gi][dd] * wk4.w;
          va[gi][0] += ta[gi][dd] * wv4.x;
          va[gi][1] += ta[gi][dd] * wv4.y;
          va[gi][2] += ta[gi][dd] * wv4.z;
          va[gi][3] += ta[gi][dd] * wv4.w;
        }
      }
    }
#pragma unroll
    for (int gi = 0; gi < 2; ++gi) {
      float4 oq, ok;
      oq.x = qa[gi][0] + bqs[j0 + 0];
      oq.y = qa[gi][1] + bqs[j0 + 1];
      oq.z = qa[gi][2] + bqs[j0 + 2];
      oq.w = qa[gi][3] + bqs[j0 + 3];
      ok.x = ka[gi][0] + bks[j0 + 0];
      ok.y = ka[gi][1] + bks[j0 + 1];
      ok.z = ka[gi][2] + bks[j0 + 2];
      ok.w = ka[gi][3] + bks[j0 + 3];
      *(float4*)&qs[g0 + gi][j0] = oq;
      *(float4*)&ks[g0 + gi][j0] = ok;
#pragma unroll
      for (int jj = 0; jj < 4; ++jj) vt[j0 + jj][g0 + gi] = va[gi][jj] + bvs[j0 + jj];
    }
  }
  __syncthreads();
  // scores 64x64: thread tile 4i x 4j
  {
    const int i0 = (tid >> 4) * 4, j0 = (tid & 15) * 4;
    float sa[4][4] = {};
#pragma unroll
    for (int d4 = 0; d4 < Dz; d4 += 4) {
      float4 qa4[4], kb4[4];
#pragma unroll
      for (int i = 0; i < 4; ++i) qa4[i] = *(float4*)&qs[i0 + i][d4];
#pragma unroll
      for (int j = 0; j < 4; ++j) kb4[j] = *(float4*)&ks[j0 + j][d4];
#pragma unroll
      for (int i = 0; i < 4; ++i)
#pragma unroll
        for (int j = 0; j < 4; ++j)
          sa[i][j] += qa4[i].x * kb4[j].x + qa4[i].y * kb4[j].y +
                      qa4[i].z * kb4[j].z + qa4[i].w * kb4[j].w;
    }
    const float scale = 0.17677669529663687f;  // 1/sqrt(32)
#pragma unroll
    for (int i = 0; i < 4; ++i) {
      float4 o;
      o.x = sa[i][0] * scale;
      o.y = sa[i][1] * scale;
      o.z = sa[i][2] * scale;
      o.w = sa[i][3] * scale;
      *(float4*)&sarr[i0 + i][j0] = o;
    }
  }
  __syncthreads();
  // softmax rows (no max-subtraction; scores are tiny)
  {
    const int r = tid >> 2, q = tid & 3;
    float e[16];
    float s = 0.f;
#pragma unroll
    for (int j4 = 0; j4 < 4; ++j4) {
      float4 v = *(float4*)&sarr[r][q * 16 + j4 * 4];
      e[j4 * 4 + 0] = __expf(v.x);
      e[j4 * 4 + 1] = __expf(v.y);
      e[j4 * 4 + 2] = __expf(v.z);
      e[j4 * 4 + 3] = __expf(v.w);
      s += e[j4 * 4 + 0] + e[j4 * 4 + 1] + e[j4 * 4 + 2] + e[j4 * 4 + 3];
    }
    s += __shfl_xor(s, 1);
    s += __shfl_xor(s, 2);
    const float inv = 1.0f / s;
#pragma unroll
    for (int j4 = 0; j4 < 4; ++j4) {
      float4 v;
      v.x = e[j4 * 4 + 0] * inv;
      v.y = e[j4 * 4 + 1] * inv;
      v.z = e[j4 * 4 + 2] * inv;
      v.w = e[j4 * 4 + 3] * inv;
      *(float4*)&sarr[r][q * 16 + j4 * 4] = v;
    }
  }
  __syncthreads();
  // out = attn @ v : thread tile 2g x 4d
  {
    const int g0 = (tid >> 3) * 2, d0 = (tid & 7) * 4;
    float oa[2][4] = {};
#pragma unroll
    for (int p4 = 0; p4 < Gz; p4 += 4) {
      float4 a0 = *(float4*)&sarr[g0][p4];
      float4 a1 = *(float4*)&sarr[g0 + 1][p4];
      const float aa[2][4] = {{a0.x, a0.y, a0.z, a0.w}, {a1.x, a1.y, a1.z, a1.w}};
      float4 vv[4];
#pragma unroll
      for (int di = 0; di < 4; ++di) vv[di] = *(float4*)&vt[d0 + di][p4];
#pragma unroll
      for (int gi = 0; gi < 2; ++gi)
#pragma unroll
        for (int di = 0; di < 4; ++di)
          oa[gi][di] += aa[gi][0] * vv[di].x + aa[gi][1] * vv[di].y +
                        aa[gi][2] * vv[di].z + aa[gi][3] * vv[di].w;
    }
#pragma unroll
    for (int gi = 0; gi < 2; ++gi) {
      float4 o;
      o.x = oa[gi][0];
      o.y = oa[gi][1];
      o.z = oa[gi][2];
      o.w = oa[gi][3];
      *(float4*)&osg[(size_t)bh * 2048 + (g0 + gi) * 32 + d0] = o;
    }
  }
}

// ---------------- recompute slice weights + scatter out_small back to points (in-place) --------
__global__ __launch_bounds__(256) void scatter_k(
    float* __restrict__ tmp, const float* __restrict__ Wslice,
    const float* __restrict__ bslice, const float* __restrict__ temp,
    const float* __restrict__ osg) {
  __shared__ __align__(16) float Wst[Gz][36];
  __shared__ __align__(16) float rows[64][36];
  __shared__ __align__(16) float wsm[64][68];
  __shared__ __align__(16) float oss[Gz][36];
  __shared__ float bsl[Gz];
  const int tid = threadIdx.x;
  const int bh = blockIdx.x, b = bh >> 3, h = bh & 7;
  for (int i = tid; i < Gz * Dz; i += 256) {
    int d = i >> 6, g = i & 63;
    Wst[g][d] = Wslice[i];
  }
  for (int i = tid; i < Gz * Dz; i += 256) oss[i >> 5][i & 31] = osg[(size_t)bh * 2048 + i];
  if (tid < Gz) bsl[tid] = bslice[tid];
  const float invt = 1.0f / temp[h];
  const size_t base = ((size_t)b * Tz + (size_t)blockIdx.y * 512) * Cz + h * Dz;
  const int lr = (tid >> 4) * 4, lg = (tid & 15) * 4;
  const int sr = tid >> 2, sq = tid & 3;
  for (int sc = 0; sc < 8; ++sc) {
    __syncthreads();
    for (int i = tid; i < 64 * 8; i += 256) {
      int r = i >> 3, kq = i & 7;
      *(float4*)&rows[r][kq * 4] =
          *(const float4*)&tmp[base + (size_t)(sc * 64 + r) * Cz + kq * 4];
    }
    __syncthreads();
    // logits
    {
      float lacc[4][4] = {};
#pragma unroll
      for (int k = 0; k < Dz; k += 4) {
        float4 av[4], bv[4];
#pragma unroll
        for (int i = 0; i < 4; ++i) av[i] = *(float4*)&rows[lr + i][k];
#pragma unroll
        for (int j = 0; j < 4; ++j) bv[j] = *(float4*)&Wst[lg + j][k];
#pragma unroll
        for (int i = 0; i < 4; ++i)
#pragma unroll
          for (int j = 0; j < 4; ++j)
            lacc[i][j] += av[i].x * bv[j].x + av[i].y * bv[j].y +
                          av[i].z * bv[j].z + av[i].w * bv[j].w;
      }
#pragma unroll
      for (int i = 0; i < 4; ++i) {
        float4 o;
        o.x = (lacc[i][0] + bsl[lg + 0]) * invt;
        o.y = (lacc[i][1] + bsl[lg + 1]) * invt;
        o.z = (lacc[i][2] + bsl[lg + 2]) * invt;
        o.w = (lacc[i][3] + bsl[lg + 3]) * invt;
        *(float4*)&wsm[lr + i][lg] = o;
      }
    }
    __syncthreads();
    // softmax in registers (thread = (row, quarter)), then scatter with q-partials
    {
      float e[16];
      float s = 0.f;
#pragma unroll
      for (int j4 = 0; j4 < 4; ++j4) {
        float4 v = *(float4*)&wsm[sr][sq * 16 + j4 * 4];
        e[j4 * 4 + 0] = __expf(v.x);
        e[j4 * 4 + 1] = __expf(v.y);
        e[j4 * 4 + 2] = __expf(v.z);
        e[j4 * 4 + 3] = __expf(v.w);
        s += e[j4 * 4 + 0] + e[j4 * 4 + 1] + e[j4 * 4 + 2] + e[j4 * 4 + 3];
      }
      s += __shfl_xor(s, 1);
      s += __shfl_xor(s, 2);
      const float inv = 1.0f / s;
#pragma unroll
      for (int i = 0; i < 16; ++i) e[i] *= inv;
      float o[32] = {};
#pragma unroll
      for (int j = 0; j < 16; ++j) {
        const int g = sq * 16 + j;
        const float w = e[j];
#pragma unroll
        for (int t8 = 0; t8 < 8; ++t8) {
          const int dq2 = (t8 + sq * 2) & 7;  // stagger to avoid bank conflicts
          float4 v = *(float4*)&oss[g][dq2 * 4];
          o[dq2 * 4 + 0] += w * v.x;
          o[dq2 * 4 + 1] += w * v.y;
          o[dq2 * 4 + 2] += w * v.z;
          o[dq2 * 4 + 3] += w * v.w;
        }
      }
#pragma unroll
      for (int i = 0; i < 32; ++i) {
        o[i] += __shfl_xor(o[i], 1);
        o[i] += __shfl_xor(o[i], 2);
      }
      if (sq == 0) {
        const size_t addr = base + (size_t)(sc * 64 + sr) * Cz;
#pragma unroll
        for (int t8 = 0; t8 < 8; ++t8) {
          float4 v;
          v.x = o[t8 * 4 + 0];
          v.y = o[t8 * 4 + 1];
          v.z = o[t8 * 4 + 2];
          v.w = o[t8 * 4 + 3];
          *(float4*)&tmp[addr + t8 * 4] = v;
        }
      }
    }
  }
}

extern "C" void kernel_launch(void* const* d_in, const int* in_sizes, int n_in,
                              void* d_out, int out_size, void* d_ws, size_t ws_size,
                              hipStream_t stream) {
  (void)in_sizes; (void)n_in; (void)out_size;
  const float* x_q = (const float*)d_in[0];
  // d_in[1] = x_r, d_in[2] = y : unused by the reference
  const float* W_in = (const float*)d_in[3];
  const float* b_in = (const float*)d_in[4];
  const float* W_slice = (const float*)d_in[5];
  const float* b_slice = (const float*)d_in[6];
  const float* temperature = (const float*)d_in[7];
  const float* W_q = (const float*)d_in[8];
  const float* b_q = (const float*)d_in[9];
  const float* W_k = (const float*)d_in[10];
  const float* b_k = (const float*)d_in[11];
  const float* W_v = (const float*)d_in[12];
  const float* b_v = (const float*)d_in[13];
  const float* W_out = (const float*)d_in[14];
  const float* b_out = (const float*)d_in[15];
  float* out = (float*)d_out;

  const size_t tmp_elems = (size_t)Bz * Tz * Cz;       // 16,777,216
  const size_t acc_elems = (size_t)Bz * Hz * Gz * Dz;  // 131,072
  const size_t norm_elems = (size_t)Bz * Hz * Gz;      // 4,096
  const size_t small_elems = acc_elems + norm_elems + acc_elems;
  const bool ws_big = ws_size >= (tmp_elems + small_elems) * sizeof(float);

  float* tmp;
  float* accg;
  if (ws_big) {
    tmp = (float*)d_ws;
    accg = tmp + tmp_elems;
  } else {
    tmp = out;  // fall back: big intermediate lives in d_out, final GEMM in-place
    accg = (float*)d_ws;
  }
  float* normg = accg + acc_elems;
  float* osg = normg + norm_elems;

  hipMemsetAsync(accg, 0, (acc_elems + norm_elems) * sizeof(float), stream);

  gemm128<<<dim3(Bz * Tz / 128, 2), 256, 0, stream>>>(x_q, W_in, b_in, tmp);
  pool_k<<<dim3(Bz * Hz, Tz / 512), 256, 0, stream>>>(tmp, W_slice, b_slice, temperature,
                                                      accg, normg);
  attn_k<<<Bz * Hz, 256, 0, stream>>>(accg, normg, W_q, b_q, W_k, b_k, W_v, b_v, osg);
  scatter_k<<<dim3(Bz * Hz, Tz / 512), 256, 0, stream>>>(tmp, W_slice, b_slice, temperature,
                                                         osg);
  if (ws_big) {
    gemm128<<<dim3(Bz * Tz / 128, 2), 256, 0, stream>>>(tmp, W_out, b_out, out);
  } else {
    gemm32ip<<<Bz * Tz / 32, 256, 0, stream>>>(out, W_out, b_out);
  }
}

// Round 2
// 623.675 us; speedup vs baseline: 9.4987x; 9.4987x over previous
//
#include <hip/hip_runtime.h>

#define Bz 8
#define Tz 8192
#define Cz 256
#define Hz 8
#define Gz 64
#define Dz 32

// ---------------- GEMM, 128x128 block tile, 8x8 micro-tile: Y = X @ W + bias ----------------
__global__ __launch_bounds__(256) void gemm128(
    const float* __restrict__ X, const float* __restrict__ W,
    const float* __restrict__ bias, float* __restrict__ Y) {
  __shared__ __align__(16) float As[16][132];  // [k][row] transposed
  __shared__ __align__(16) float Bs[16][132];  // [k][col]
  const int tid = threadIdx.x;
  const size_t m0 = (size_t)blockIdx.x * 128;
  const int n0 = blockIdx.y * 128;
  const int tx = tid & 15, ty = tid >> 4;
  const int r0 = ty * 8, c0 = tx * 8;
  float acc[8][8] = {};
  for (int kt = 0; kt < Cz; kt += 16) {
    __syncthreads();
#pragma unroll
    for (int u = 0; u < 2; ++u) {
      int idx = tid + u * 256;          // 512 float4 of A tile
      int row = idx >> 2, kq = idx & 3;
      float4 v = *(const float4*)&X[(m0 + row) * Cz + kt + kq * 4];
      As[kq * 4 + 0][row] = v.x;
      As[kq * 4 + 1][row] = v.y;
      As[kq * 4 + 2][row] = v.z;
      As[kq * 4 + 3][row] = v.w;
    }
#pragma unroll
    for (int u = 0; u < 2; ++u) {
      int idx = tid + u * 256;          // 512 float4 of B tile
      int k = idx >> 5, cq = idx & 31;
      *(float4*)&Bs[k][cq * 4] = *(const float4*)&W[(size_t)(kt + k) * Cz + n0 + cq * 4];
    }
    __syncthreads();
#pragma unroll
    for (int kk = 0; kk < 16; ++kk) {
      float4 a0 = *(float4*)&As[kk][r0];
      float4 a1 = *(float4*)&As[kk][r0 + 4];
      float4 b0 = *(float4*)&Bs[kk][c0];
      float4 b1 = *(float4*)&Bs[kk][c0 + 4];
      float av[8] = {a0.x, a0.y, a0.z, a0.w, a1.x, a1.y, a1.z, a1.w};
      float bv[8] = {b0.x, b0.y, b0.z, b0.w, b1.x, b1.y, b1.z, b1.w};
#pragma unroll
      for (int i = 0; i < 8; ++i)
#pragma unroll
        for (int j = 0; j < 8; ++j) acc[i][j] += av[i] * bv[j];
    }
  }
#pragma unroll
  for (int i = 0; i < 8; ++i) {
    size_t row = m0 + r0 + i;
#pragma unroll
    for (int jq = 0; jq < 2; ++jq) {
      float4 o;
      o.x = acc[i][jq * 4 + 0] + bias[n0 + c0 + jq * 4 + 0];
      o.y = acc[i][jq * 4 + 1] + bias[n0 + c0 + jq * 4 + 1];
      o.z = acc[i][jq * 4 + 2] + bias[n0 + c0 + jq * 4 + 2];
      o.w = acc[i][jq * 4 + 3] + bias[n0 + c0 + jq * 4 + 3];
      *(float4*)&Y[row * Cz + n0 + c0 + jq * 4] = o;
    }
  }
}

// ---------------- Fallback: in-place GEMM (32 rows x full 256 cols per block) ----------------
__global__ __launch_bounds__(256) void gemm32ip(
    float* __restrict__ Y, const float* __restrict__ W, const float* __restrict__ bias) {
  __shared__ __align__(16) float As[32][260];  // full K rows staged (in-place safety)
  __shared__ __align__(16) float Bs[16][260];
  const int tid = threadIdx.x;
  const size_t m0 = (size_t)blockIdx.x * 32;
  for (int idx = tid; idx < 32 * 64; idx += 256) {
    int row = idx >> 6, kq = idx & 63;
    *(float4*)&As[row][kq * 4] = *(const float4*)&Y[(m0 + row) * Cz + kq * 4];
  }
  const int tx = tid & 31, ty = tid >> 5;
  const int r0 = ty * 4, c0 = tx * 4;  // cols c0..c0+3 and c0+128..c0+131
  float acc[4][8] = {};
  for (int kt = 0; kt < Cz; kt += 16) {
    __syncthreads();
#pragma unroll
    for (int u = 0; u < 4; ++u) {
      int idx = tid + u * 256;
      int k = idx >> 6, cq = idx & 63;
      *(float4*)&Bs[k][cq * 4] = *(const float4*)&W[(size_t)(kt + k) * Cz + cq * 4];
    }
    __syncthreads();
#pragma unroll
    for (int kk = 0; kk < 16; kk += 4) {
      float4 a4[4];
#pragma unroll
      for (int i = 0; i < 4; ++i) a4[i] = *(float4*)&As[r0 + i][kt + kk];
      float am[4][4];
#pragma unroll
      for (int i = 0; i < 4; ++i) {
        am[i][0] = a4[i].x; am[i][1] = a4[i].y; am[i][2] = a4[i].z; am[i][3] = a4[i].w;
      }
#pragma unroll
      for (int k2 = 0; k2 < 4; ++k2) {
        float4 b0 = *(float4*)&Bs[kk + k2][c0];
        float4 b1 = *(float4*)&Bs[kk + k2][c0 + 128];
#pragma unroll
        for (int i = 0; i < 4; ++i) {
          acc[i][0] += am[i][k2] * b0.x;
          acc[i][1] += am[i][k2] * b0.y;
          acc[i][2] += am[i][k2] * b0.z;
          acc[i][3] += am[i][k2] * b0.w;
          acc[i][4] += am[i][k2] * b1.x;
          acc[i][5] += am[i][k2] * b1.y;
          acc[i][6] += am[i][k2] * b1.z;
          acc[i][7] += am[i][k2] * b1.w;
        }
      }
    }
  }
#pragma unroll
  for (int i = 0; i < 4; ++i) {
    size_t row = m0 + r0 + i;
    float4 o0, o1;
    o0.x = acc[i][0] + bias[c0 + 0];
    o0.y = acc[i][1] + bias[c0 + 1];
    o0.z = acc[i][2] + bias[c0 + 2];
    o0.w = acc[i][3] + bias[c0 + 3];
    o1.x = acc[i][4] + bias[c0 + 128];
    o1.y = acc[i][5] + bias[c0 + 129];
    o1.z = acc[i][6] + bias[c0 + 130];
    o1.w = acc[i][7] + bias[c0 + 131];
    *(float4*)&Y[row * Cz + c0] = o0;
    *(float4*)&Y[row * Cz + c0 + 128] = o1;
  }
}

// ---------------- slice logits -> softmax -> weighted pooling (token accumulation) ----------------
__global__ __launch_bounds__(256) void pool_k(
    const float* __restrict__ tmp, const float* __restrict__ Wslice,
    const float* __restrict__ bslice, const float* __restrict__ temp,
    float* __restrict__ accg, float* __restrict__ normg) {
  __shared__ __align__(16) float Wst[Gz][36];   // [g][d] (transposed W_slice)
  __shared__ __align__(16) float rows[64][36];  // [r][d]
  __shared__ __align__(16) float wsm[64][68];   // [r][g] logits / weights
  __shared__ float bsl[Gz];
  __shared__ float accr[Gz][Dz];
  __shared__ float accn[Gz];
  const int tid = threadIdx.x;
  const int bh = blockIdx.x, b = bh >> 3, h = bh & 7;
  for (int i = tid; i < Gz * Dz; i += 256) {
    int d = i >> 6, g = i & 63;
    Wst[g][d] = Wslice[i];       // W_slice is (D,G) row-major
    ((float*)accr)[i] = 0.f;
  }
  if (tid < Gz) { bsl[tid] = bslice[tid]; accn[tid] = 0.f; }
  const float invt = 1.0f / temp[h];
  const int gg = tid & 15, dq = (tid >> 4) & 3, rh = tid >> 6;
  const int g0 = gg * 4, d0 = dq * 8;
  const int lr = (tid >> 4) * 4, lg = (tid & 15) * 4;
  const int sr = tid >> 2, sq = tid & 3;
  float pacc[4][8] = {};
  float pnorm[4] = {0.f, 0.f, 0.f, 0.f};
  const size_t base = ((size_t)b * Tz + (size_t)blockIdx.y * 512) * Cz + h * Dz;
  for (int sc = 0; sc < 8; ++sc) {
    __syncthreads();
    for (int i = tid; i < 64 * 8; i += 256) {
      int r = i >> 3, kq = i & 7;
      *(float4*)&rows[r][kq * 4] =
          *(const float4*)&tmp[base + (size_t)(sc * 64 + r) * Cz + kq * 4];
    }
    __syncthreads();
    // logits: 4r x 4g per thread
    {
      float lacc[4][4] = {};
#pragma unroll
      for (int k = 0; k < Dz; k += 4) {
        float4 av[4], bv[4];
#pragma unroll
        for (int i = 0; i < 4; ++i) av[i] = *(float4*)&rows[lr + i][k];
#pragma unroll
        for (int j = 0; j < 4; ++j) bv[j] = *(float4*)&Wst[lg + j][k];
#pragma unroll
        for (int i = 0; i < 4; ++i)
#pragma unroll
          for (int j = 0; j < 4; ++j)
            lacc[i][j] += av[i].x * bv[j].x + av[i].y * bv[j].y +
                          av[i].z * bv[j].z + av[i].w * bv[j].w;
      }
#pragma unroll
      for (int i = 0; i < 4; ++i) {
        float4 o;
        o.x = (lacc[i][0] + bsl[lg + 0]) * invt;
        o.y = (lacc[i][1] + bsl[lg + 1]) * invt;
        o.z = (lacc[i][2] + bsl[lg + 2]) * invt;
        o.w = (lacc[i][3] + bsl[lg + 3]) * invt;
        *(float4*)&wsm[lr + i][lg] = o;
      }
    }
    __syncthreads();
    // softmax over g (no max-subtraction: |logit| < ~1.3), 4 threads per row
    {
      float e[16];
      float s = 0.f;
#pragma unroll
      for (int j4 = 0; j4 < 4; ++j4) {
        float4 v = *(float4*)&wsm[sr][sq * 16 + j4 * 4];
        e[j4 * 4 + 0] = __expf(v.x);
        e[j4 * 4 + 1] = __expf(v.y);
        e[j4 * 4 + 2] = __expf(v.z);
        e[j4 * 4 + 3] = __expf(v.w);
        s += e[j4 * 4 + 0] + e[j4 * 4 + 1] + e[j4 * 4 + 2] + e[j4 * 4 + 3];
      }
      s += __shfl_xor(s, 1);
      s += __shfl_xor(s, 2);
      const float inv = 1.0f / s;
#pragma unroll
      for (int j4 = 0; j4 < 4; ++j4) {
        float4 v;
        v.x = e[j4 * 4 + 0] * inv;
        v.y = e[j4 * 4 + 1] * inv;
        v.z = e[j4 * 4 + 2] * inv;
        v.w = e[j4 * 4 + 3] * inv;
        *(float4*)&wsm[sr][sq * 16 + j4 * 4] = v;
      }
    }
    __syncthreads();
    // accumulate: thread owns (4g x 8d), 16 rows slice (rh)
#pragma unroll
    for (int rr = 0; rr < 16; ++rr) {
      const int r = rh * 16 + rr;
      float4 w4 = *(float4*)&wsm[r][g0];
      float4 ra = *(float4*)&rows[r][d0];
      float4 rb = *(float4*)&rows[r][d0 + 4];
      const float wv[4] = {w4.x, w4.y, w4.z, w4.w};
      const float rv[8] = {ra.x, ra.y, ra.z, ra.w, rb.x, rb.y, rb.z, rb.w};
#pragma unroll
      for (int i = 0; i < 4; ++i)
#pragma unroll
        for (int j = 0; j < 8; ++j) pacc[i][j] += wv[i] * rv[j];
      if (dq == 0) {
#pragma unroll
        for (int i = 0; i < 4; ++i) pnorm[i] += wv[i];
      }
    }
  }
  __syncthreads();
#pragma unroll
  for (int i = 0; i < 4; ++i)
#pragma unroll
    for (int j = 0; j < 8; ++j) atomicAdd(&accr[g0 + i][d0 + j], pacc[i][j]);
  if (dq == 0) {
#pragma unroll
    for (int i = 0; i < 4; ++i) atomicAdd(&accn[g0 + i], pnorm[i]);
  }
  __syncthreads();
  for (int i = tid; i < Gz * Dz; i += 256)
    atomicAdd(&accg[(size_t)bh * Gz * Dz + i], ((float*)accr)[i]);
  if (tid < Gz) atomicAdd(&normg[bh * Gz + tid], accn[tid]);
}

// ---------------- tiny per-(b,h) attention over G=64 slice tokens ----------------
__global__ __launch_bounds__(256) void attn_k(
    const float* __restrict__ accg, const float* __restrict__ normg,
    const float* __restrict__ Wq, const float* __restrict__ bq,
    const float* __restrict__ Wk, const float* __restrict__ bk,
    const float* __restrict__ Wv, const float* __restrict__ bv,
    float* __restrict__ osg) {
  __shared__ __align__(16) char pool[50560];
  float(*tok)[36] = (float(*)[36])pool;               // 64x36
  float(*wqs)[36] = (float(*)[36])(pool + 9216);      // 32x36
  float(*wks)[36] = (float(*)[36])(pool + 13824);
  float(*wvs)[36] = (float(*)[36])(pool + 18432);     // ends 23040
  float(*sarr)[68] = (float(*)[68])pool;              // 64x68, aliases tok/wqs/wks (dead then)
  float(*qs)[36] = (float(*)[36])(pool + 23040);
  float(*ks)[36] = (float(*)[36])(pool + 32256);
  float(*vt)[68] = (float(*)[68])(pool + 41472);      // 32x68 (v transposed) ends 50176
  float* bqs = (float*)(pool + 50176);
  float* bks = bqs + 32;
  float* bvs = bks + 32;
  const int tid = threadIdx.x;
  const int bh = blockIdx.x;
  for (int i = tid; i < Gz * Dz; i += 256) {
    int g = i >> 5;
    tok[g][i & 31] = accg[(size_t)bh * 2048 + i] / (normg[bh * 64 + g] + 1e-5f);
  }
  for (int i = tid; i < Dz * Dz; i += 256) {
    int d = i >> 5, j = i & 31;
    wqs[d][j] = Wq[i];
    wks[d][j] = Wk[i];
    wvs[d][j] = Wv[i];
  }
  if (tid < 32) { bqs[tid] = bq[tid]; bks[tid] = bk[tid]; bvs[tid] = bv[tid]; }
  __syncthreads();
  // projections: thread tile 2g x 4j, fused q/k/v
  {
    const int g0 = (tid >> 3) * 2, j0 = (tid & 7) * 4;
    float qa[2][4] = {}, ka[2][4] = {}, va[2][4] = {};
#pragma unroll
    for (int d4 = 0; d4 < Dz; d4 += 4) {
      float4 t0 = *(float4*)&tok[g0][d4];
      float4 t1 = *(float4*)&tok[g0 + 1][d4];
      const float ta[2][4] = {{t0.x, t0.y, t0.z, t0.w}, {t1.x, t1.y, t1.z, t1.w}};
#pragma unroll
      for (int dd = 0; dd < 4; ++dd) {
        float4 wq4 = *(float4*)&wqs[d4 + dd][j0];
        float4 wk4 = *(float4*)&wks[d4 + dd][j0];
        float4 wv4 = *(float4*)&wvs[d4 + dd][j0];
#pragma unroll
        for (int gi = 0; gi < 2; ++gi) {
          qa[gi][0] += ta[gi][dd] * wq4.x;
          qa[gi][1] += ta[gi][dd] * wq4.y;
          qa[gi][2] += ta[gi][dd] * wq4.z;
          qa[gi][3] += ta[gi][dd] * wq4.w;
          ka[gi][0] += ta[gi][dd] * wk4.x;
          ka[gi][1] += ta[gi][dd] * wk4.y;
          ka[gi][2] += ta[gi][dd] * wk4.z;
          ka[gi][3] += ta[gi][dd] * wk4.w;
          va[gi][0] += ta[gi][dd] * wv4.x;
          va[gi][1] += ta[gi][dd] * wv4.y;
          va[gi][2] += ta[gi][dd] * wv4.z;
          va[gi][3] += ta[gi][dd] * wv4.w;
        }
      }
    }
#pragma unroll
    for (int gi = 0; gi < 2; ++gi) {
      float4 oq, ok;
      oq.x = qa[gi][0] + bqs[j0 + 0];
      oq.y = qa[gi][1] + bqs[j0 + 1];
      oq.z = qa[gi][2] + bqs[j0 + 2];
      oq.w = qa[gi][3] + bqs[j0 + 3];
      ok.x = ka[gi][0] + bks[j0 + 0];
      ok.y = ka[gi][1] + bks[j0 + 1];
      ok.z = ka[gi][2] + bks[j0 + 2];
      ok.w = ka[gi][3] + bks[j0 + 3];
      *(float4*)&qs[g0 + gi][j0] = oq;
      *(float4*)&ks[g0 + gi][j0] = ok;
#pragma unroll
      for (int jj = 0; jj < 4; ++jj) vt[j0 + jj][g0 + gi] = va[gi][jj] + bvs[j0 + jj];
    }
  }
  __syncthreads();
  // scores 64x64: thread tile 4i x 4j
  {
    const int i0 = (tid >> 4) * 4, j0 = (tid & 15) * 4;
    float sa[4][4] = {};
#pragma unroll
    for (int d4 = 0; d4 < Dz; d4 += 4) {
      float4 qa4[4], kb4[4];
#pragma unroll
      for (int i = 0; i < 4; ++i) qa4[i] = *(float4*)&qs[i0 + i][d4];
#pragma unroll
      for (int j = 0; j < 4; ++j) kb4[j] = *(float4*)&ks[j0 + j][d4];
#pragma unroll
      for (int i = 0; i < 4; ++i)
#pragma unroll
        for (int j = 0; j < 4; ++j)
          sa[i][j] += qa4[i].x * kb4[j].x + qa4[i].y * kb4[j].y +
                      qa4[i].z * kb4[j].z + qa4[i].w * kb4[j].w;
    }
    const float scale = 0.17677669529663687f;  // 1/sqrt(32)
#pragma unroll
    for (int i = 0; i < 4; ++i) {
      float4 o;
      o.x = sa[i][0] * scale;
      o.y = sa[i][1] * scale;
      o.z = sa[i][2] * scale;
      o.w = sa[i][3] * scale;
      *(float4*)&sarr[i0 + i][j0] = o;
    }
  }
  __syncthreads();
  // softmax rows (no max-subtraction; scores are tiny)
  {
    const int r = tid >> 2, q = tid & 3;
    float e[16];
    float s = 0.f;
#pragma unroll
    for (int j4 = 0; j4 < 4; ++j4) {
      float4 v = *(float4*)&sarr[r][q * 16 + j4 * 4];
      e[j4 * 4 + 0] = __expf(v.x);
      e[j4 * 4 + 1] = __expf(v.y);
      e[j4 * 4 + 2] = __expf(v.z);
      e[j4 * 4 + 3] = __expf(v.w);
      s += e[j4 * 4 + 0] + e[j4 * 4 + 1] + e[j4 * 4 + 2] + e[j4 * 4 + 3];
    }
    s += __shfl_xor(s, 1);
    s += __shfl_xor(s, 2);
    const float inv = 1.0f / s;
#pragma unroll
    for (int j4 = 0; j4 < 4; ++j4) {
      float4 v;
      v.x = e[j4 * 4 + 0] * inv;
      v.y = e[j4 * 4 + 1] * inv;
      v.z = e[j4 * 4 + 2] * inv;
      v.w = e[j4 * 4 + 3] * inv;
      *(float4*)&sarr[r][q * 16 + j4 * 4] = v;
    }
  }
  __syncthreads();
  // out = attn @ v : thread tile 2g x 4d
  {
    const int g0 = (tid >> 3) * 2, d0 = (tid & 7) * 4;
    float oa[2][4] = {};
#pragma unroll
    for (int p4 = 0; p4 < Gz; p4 += 4) {
      float4 a0 = *(float4*)&sarr[g0][p4];
      float4 a1 = *(float4*)&sarr[g0 + 1][p4];
      const float aa[2][4] = {{a0.x, a0.y, a0.z, a0.w}, {a1.x, a1.y, a1.z, a1.w}};
      float4 vv[4];
#pragma unroll
      for (int di = 0; di < 4; ++di) vv[di] = *(float4*)&vt[d0 + di][p4];
#pragma unroll
      for (int gi = 0; gi < 2; ++gi)
#pragma unroll
        for (int di = 0; di < 4; ++di)
          oa[gi][di] += aa[gi][0] * vv[di].x + aa[gi][1] * vv[di].y +
                        aa[gi][2] * vv[di].z + aa[gi][3] * vv[di].w;
    }
#pragma unroll
    for (int gi = 0; gi < 2; ++gi) {
      float4 o;
      o.x = oa[gi][0];
      o.y = oa[gi][1];
      o.z = oa[gi][2];
      o.w = oa[gi][3];
      *(float4*)&osg[(size_t)bh * 2048 + (g0 + gi) * 32 + d0] = o;
    }
  }
}

// ---------------- recompute slice weights + scatter out_small back to points (in-place) --------
// out[r][d] = sum_g softmax(logits)[r][g] * osg[g][d]  -- done as a small LDS GEMM.
__global__ __launch_bounds__(256) void scatter_k(
    float* __restrict__ tmp, const float* __restrict__ Wslice,
    const float* __restrict__ bslice, const float* __restrict__ temp,
    const float* __restrict__ osg) {
  __shared__ __align__(16) float Wst[Gz][36];   // [g][d]
  __shared__ __align__(16) float rows[64][36];  // [r][d]
  __shared__ __align__(16) float wsm[64][68];   // [r][g] logits / weights
  __shared__ __align__(16) float oss[Gz][36];   // [g][d] slice-attention outputs
  __shared__ float bsl[Gz];
  const int tid = threadIdx.x;
  const int bh = blockIdx.x, b = bh >> 3, h = bh & 7;
  for (int i = tid; i < Gz * Dz; i += 256) {
    int d = i >> 6, g = i & 63;
    Wst[g][d] = Wslice[i];
  }
  for (int i = tid; i < Gz * Dz; i += 256) oss[i >> 5][i & 31] = osg[(size_t)bh * 2048 + i];
  if (tid < Gz) bsl[tid] = bslice[tid];
  const float invt = 1.0f / temp[h];
  const size_t base = ((size_t)b * Tz + (size_t)blockIdx.y * 512) * Cz + h * Dz;
  const int lr = (tid >> 4) * 4, lg = (tid & 15) * 4;   // logits tile 4r x 4g
  const int sr = tid >> 2, sq = tid & 3;                // softmax: 4 threads / row
  const int orow = (tid >> 3) * 2, od = (tid & 7) * 4;  // output tile 2r x 4d
  for (int sc = 0; sc < 8; ++sc) {
    __syncthreads();
    for (int i = tid; i < 64 * 8; i += 256) {
      int r = i >> 3, kq = i & 7;
      *(float4*)&rows[r][kq * 4] =
          *(const float4*)&tmp[base + (size_t)(sc * 64 + r) * Cz + kq * 4];
    }
    __syncthreads();
    // logits: 4r x 4g per thread
    {
      float lacc[4][4] = {};
#pragma unroll
      for (int k = 0; k < Dz; k += 4) {
        float4 av[4], bv[4];
#pragma unroll
        for (int i = 0; i < 4; ++i) av[i] = *(float4*)&rows[lr + i][k];
#pragma unroll
        for (int j = 0; j < 4; ++j) bv[j] = *(float4*)&Wst[lg + j][k];
#pragma unroll
        for (int i = 0; i < 4; ++i)
#pragma unroll
          for (int j = 0; j < 4; ++j)
            lacc[i][j] += av[i].x * bv[j].x + av[i].y * bv[j].y +
                          av[i].z * bv[j].z + av[i].w * bv[j].w;
      }
#pragma unroll
      for (int i = 0; i < 4; ++i) {
        float4 o;
        o.x = (lacc[i][0] + bsl[lg + 0]) * invt;
        o.y = (lacc[i][1] + bsl[lg + 1]) * invt;
        o.z = (lacc[i][2] + bsl[lg + 2]) * invt;
        o.w = (lacc[i][3] + bsl[lg + 3]) * invt;
        *(float4*)&wsm[lr + i][lg] = o;
      }
    }
    __syncthreads();
    // softmax over g, normalized weights written back to wsm
    {
      float e[16];
      float s = 0.f;
#pragma unroll
      for (int j4 = 0; j4 < 4; ++j4) {
        float4 v = *(float4*)&wsm[sr][sq * 16 + j4 * 4];
        e[j4 * 4 + 0] = __expf(v.x);
        e[j4 * 4 + 1] = __expf(v.y);
        e[j4 * 4 + 2] = __expf(v.z);
        e[j4 * 4 + 3] = __expf(v.w);
        s += e[j4 * 4 + 0] + e[j4 * 4 + 1] + e[j4 * 4 + 2] + e[j4 * 4 + 3];
      }
      s += __shfl_xor(s, 1);
      s += __shfl_xor(s, 2);
      const float inv = 1.0f / s;
#pragma unroll
      for (int j4 = 0; j4 < 4; ++j4) {
        float4 v;
        v.x = e[j4 * 4 + 0] * inv;
        v.y = e[j4 * 4 + 1] * inv;
        v.z = e[j4 * 4 + 2] * inv;
        v.w = e[j4 * 4 + 3] * inv;
        *(float4*)&wsm[sr][sq * 16 + j4 * 4] = v;
      }
    }
    __syncthreads();
    // out = wsm @ oss : thread tile 2r x 4d, g-steps of 4 (all static indexing)
    {
      float oa[2][4] = {};
#pragma unroll
      for (int g = 0; g < Gz; g += 4) {
        float4 w0 = *(float4*)&wsm[orow][g];
        float4 w1 = *(float4*)&wsm[orow + 1][g];
        float4 v0 = *(float4*)&oss[g + 0][od];
        float4 v1 = *(float4*)&oss[g + 1][od];
        float4 v2 = *(float4*)&oss[g + 2][od];
        float4 v3 = *(float4*)&oss[g + 3][od];
        oa[0][0] += w0.x * v0.x + w0.y * v1.x + w0.z * v2.x + w0.w * v3.x;
        oa[0][1] += w0.x * v0.y + w0.y * v1.y + w0.z * v2.y + w0.w * v3.y;
        oa[0][2] += w0.x * v0.z + w0.y * v1.z + w0.z * v2.z + w0.w * v3.z;
        oa[0][3] += w0.x * v0.w + w0.y * v1.w + w0.z * v2.w + w0.w * v3.w;
        oa[1][0] += w1.x * v0.x + w1.y * v1.x + w1.z * v2.x + w1.w * v3.x;
        oa[1][1] += w1.x * v0.y + w1.y * v1.y + w1.z * v2.y + w1.w * v3.y;
        oa[1][2] += w1.x * v0.z + w1.y * v1.z + w1.z * v2.z + w1.w * v3.z;
        oa[1][3] += w1.x * v0.w + w1.y * v1.w + w1.z * v2.w + w1.w * v3.w;
      }
#pragma unroll
      for (int gi = 0; gi < 2; ++gi) {
        float4 o;
        o.x = oa[gi][0];
        o.y = oa[gi][1];
        o.z = oa[gi][2];
        o.w = oa[gi][3];
        *(float4*)&tmp[base + (size_t)(sc * 64 + orow + gi) * Cz + od] = o;
      }
    }
  }
}

extern "C" void kernel_launch(void* const* d_in, const int* in_sizes, int n_in,
                              void* d_out, int out_size, void* d_ws, size_t ws_size,
                              hipStream_t stream) {
  (void)in_sizes; (void)n_in; (void)out_size;
  const float* x_q = (const float*)d_in[0];
  // d_in[1] = x_r, d_in[2] = y : unused by the reference
  const float* W_in = (const float*)d_in[3];
  const float* b_in = (const float*)d_in[4];
  const float* W_slice = (const float*)d_in[5];
  const float* b_slice = (const float*)d_in[6];
  const float* temperature = (const float*)d_in[7];
  const float* W_q = (const float*)d_in[8];
  const float* b_q = (const float*)d_in[9];
  const float* W_k = (const float*)d_in[10];
  const float* b_k = (const float*)d_in[11];
  const float* W_v = (const float*)d_in[12];
  const float* b_v = (const float*)d_in[13];
  const float* W_out = (const float*)d_in[14];
  const float* b_out = (const float*)d_in[15];
  float* out = (float*)d_out;

  const size_t tmp_elems = (size_t)Bz * Tz * Cz;       // 16,777,216
  const size_t acc_elems = (size_t)Bz * Hz * Gz * Dz;  // 131,072
  const size_t norm_elems = (size_t)Bz * Hz * Gz;      // 4,096
  const size_t small_elems = acc_elems + norm_elems + acc_elems;
  const bool ws_big = ws_size >= (tmp_elems + small_elems) * sizeof(float);

  float* tmp;
  float* accg;
  if (ws_big) {
    tmp = (float*)d_ws;
    accg = tmp + tmp_elems;
  } else {
    tmp = out;  // fall back: big intermediate lives in d_out, final GEMM in-place
    accg = (float*)d_ws;
  }
  float* normg = accg + acc_elems;
  float* osg = normg + norm_elems;

  hipMemsetAsync(accg, 0, (acc_elems + norm_elems) * sizeof(float), stream);

  gemm128<<<dim3(Bz * Tz / 128, 2), 256, 0, stream>>>(x_q, W_in, b_in, tmp);
  pool_k<<<dim3(Bz * Hz, Tz / 512), 256, 0, stream>>>(tmp, W_slice, b_slice, temperature,
                                                      accg, normg);
  attn_k<<<Bz * Hz, 256, 0, stream>>>(accg, normg, W_q, b_q, W_k, b_k, W_v, b_v, osg);
  scatter_k<<<dim3(Bz * Hz, Tz / 512), 256, 0, stream>>>(tmp, W_slice, b_slice, temperature,
                                                         osg);
  if (ws_big) {
    gemm128<<<dim3(Bz * Tz / 128, 2), 256, 0, stream>>>(tmp, W_out, b_out, out);
  } else {
    gemm32ip<<<Bz * Tz / 32, 256, 0, stream>>>(out, W_out, b_out);
  }
}

// Round 3
// 496.437 us; speedup vs baseline: 11.9332x; 1.2563x over previous
//
#include <hip/hip_runtime.h>

#define Bz 8
#define Tz 8192
#define Cz 256
#define Hz 8
#define Gz 64
#define Dz 32

typedef __bf16 bf16x8 __attribute__((ext_vector_type(8)));
typedef float f32x4 __attribute__((ext_vector_type(4)));

__device__ inline void splitbf(float x, unsigned short& h, unsigned short& l) {
  __bf16 hb = (__bf16)x;
  float r = x - (float)hb;
  __bf16 lb = (__bf16)r;
  h = __builtin_bit_cast(unsigned short, hb);
  l = __builtin_bit_cast(unsigned short, lb);
}

// ---------------- prep: split W (K x N) into bf16 hi/lo, transposed to [n][k] ----------------
__global__ __launch_bounds__(256) void prep_k(
    const float* __restrict__ Win, const float* __restrict__ Wout,
    unsigned short* __restrict__ winh, unsigned short* __restrict__ winl,
    unsigned short* __restrict__ wouth, unsigned short* __restrict__ woutl) {
  const int k = blockIdx.x, n = threadIdx.x;
  unsigned short h, l;
  splitbf(Win[k * Cz + n], h, l);
  winh[n * Cz + k] = h;
  winl[n * Cz + k] = l;
  splitbf(Wout[k * Cz + n], h, l);
  wouth[n * Cz + k] = h;
  woutl[n * Cz + k] = l;
}

// ---------------- split-bf16 MFMA GEMM: Y = X @ W + bias (W pre-split as Wt[n][k]) ----------
// 128x128 tile, 4 waves (64x64 each), 16x16x32 bf16 MFMA, 3 MFMA per product (hi*hi+hi*lo+lo*hi).
// Block reads only X rows [m0,m0+128) and writes the same Y rows -> in-place (Y==X) is safe.
__global__ __launch_bounds__(256, 3) void gemm_mfma(
    const float* __restrict__ X, const unsigned short* __restrict__ Wh,
    const unsigned short* __restrict__ Wl, const float* __restrict__ bias, float* Y) {
  __shared__ __align__(16) unsigned short Ah[128][40];
  __shared__ __align__(16) unsigned short Al[128][40];
  __shared__ __align__(16) unsigned short Bth[128][40];
  __shared__ __align__(16) unsigned short Btl[128][40];
  const int tid = threadIdx.x;
  const size_t m0 = (size_t)blockIdx.x * 128;
  const int n0 = blockIdx.y * 128;
  const int lane = tid & 63, wave = tid >> 6;
  const int lm = lane & 15, quad = lane >> 4, k8 = quad * 8;
  const int wm = (wave & 1) * 64, wn = (wave >> 1) * 64;
  f32x4 acc[4][4] = {};
  for (int kt = 0; kt < Cz; kt += 32) {
    __syncthreads();
    // stage A (fp32 -> bf16 hi/lo): 128 rows x 32 k
#pragma unroll
    for (int u = 0; u < 4; ++u) {
      int idx = tid + u * 256;
      int row = idx >> 3, q = idx & 7;
      float4 v = *(const float4*)&X[(m0 + row) * Cz + kt + q * 4];
      unsigned short h0, l0, h1, l1, h2, l2, h3, l3;
      splitbf(v.x, h0, l0);
      splitbf(v.y, h1, l1);
      splitbf(v.z, h2, l2);
      splitbf(v.w, h3, l3);
      ushort4 hv = {h0, h1, h2, h3};
      ushort4 lv = {l0, l1, l2, l3};
      *(ushort4*)&Ah[row][q * 4] = hv;
      *(ushort4*)&Al[row][q * 4] = lv;
    }
    // stage B from pre-split Wt[n][k]: 128 n-rows x 32 k halves
#pragma unroll
    for (int u = 0; u < 2; ++u) {
      int idx = tid + u * 256;
      int row = idx >> 2, q = idx & 3;
      uint4 hv = *(const uint4*)&Wh[(size_t)(n0 + row) * Cz + kt + q * 8];
      uint4 lv = *(const uint4*)&Wl[(size_t)(n0 + row) * Cz + kt + q * 8];
      *(uint4*)&Bth[row][q * 8] = hv;
      *(uint4*)&Btl[row][q * 8] = lv;
    }
    __syncthreads();
    bf16x8 bh[4], bl[4];
#pragma unroll
    for (int nt = 0; nt < 4; ++nt) {
      bh[nt] = *(const bf16x8*)&Bth[wn + nt * 16 + lm][k8];
      bl[nt] = *(const bf16x8*)&Btl[wn + nt * 16 + lm][k8];
    }
#pragma unroll
    for (int mt = 0; mt < 4; ++mt) {
      bf16x8 ah = *(const bf16x8*)&Ah[wm + mt * 16 + lm][k8];
      bf16x8 alo = *(const bf16x8*)&Al[wm + mt * 16 + lm][k8];
#pragma unroll
      for (int nt = 0; nt < 4; ++nt) {
        acc[mt][nt] = __builtin_amdgcn_mfma_f32_16x16x32_bf16(alo, bh[nt], acc[mt][nt], 0, 0, 0);
        acc[mt][nt] = __builtin_amdgcn_mfma_f32_16x16x32_bf16(ah, bl[nt], acc[mt][nt], 0, 0, 0);
        acc[mt][nt] = __builtin_amdgcn_mfma_f32_16x16x32_bf16(ah, bh[nt], acc[mt][nt], 0, 0, 0);
      }
    }
  }
  float bcol[4];
#pragma unroll
  for (int nt = 0; nt < 4; ++nt) bcol[nt] = bias[n0 + wn + nt * 16 + lm];
#pragma unroll
  for (int mt = 0; mt < 4; ++mt)
#pragma unroll
    for (int nt = 0; nt < 4; ++nt)
#pragma unroll
      for (int r = 0; r < 4; ++r) {
        size_t row = m0 + wm + mt * 16 + quad * 4 + r;
        Y[row * Cz + n0 + wn + nt * 16 + lm] = acc[mt][nt][r] + bcol[nt];
      }
}

// ---------------- slice logits -> softmax -> weighted pooling (token accumulation) ----------------
__global__ __launch_bounds__(256) void pool_k(
    const float* __restrict__ tmp, const float* __restrict__ Wslice,
    const float* __restrict__ bslice, const float* __restrict__ temp,
    float* __restrict__ accg, float* __restrict__ normg) {
  __shared__ __align__(16) float Wst[Gz][36];   // [g][d] (transposed W_slice)
  __shared__ __align__(16) float rows[64][36];  // [r][d]
  __shared__ __align__(16) float wsm[64][68];   // [r][g] logits / weights
  __shared__ float bsl[Gz];
  __shared__ float accr[Gz][Dz];
  __shared__ float accn[Gz];
  const int tid = threadIdx.x;
  const int bh = blockIdx.x, b = bh >> 3, h = bh & 7;
  for (int i = tid; i < Gz * Dz; i += 256) {
    int d = i >> 6, g = i & 63;
    Wst[g][d] = Wslice[i];  // W_slice is (D,G) row-major
    ((float*)accr)[i] = 0.f;
  }
  if (tid < Gz) { bsl[tid] = bslice[tid]; accn[tid] = 0.f; }
  const float invt = 1.0f / temp[h];
  const int gg = tid & 15, dq = (tid >> 4) & 3, rh = tid >> 6;
  const int g0 = gg * 4, d0 = dq * 8;
  const int lr = (tid >> 4) * 4, lgi = tid & 15;  // interleaved g: lgi + 16j (bank-conflict-free)
  const int sr = tid >> 2, sq = tid & 3;
  float pacc[4][8] = {};
  float pnorm[4] = {0.f, 0.f, 0.f, 0.f};
  const size_t base = ((size_t)b * Tz + (size_t)blockIdx.y * 512) * Cz + h * Dz;
  for (int sc = 0; sc < 8; ++sc) {
    __syncthreads();
    for (int i = tid; i < 64 * 8; i += 256) {
      int r = i >> 3, kq = i & 7;
      *(float4*)&rows[r][kq * 4] =
          *(const float4*)&tmp[base + (size_t)(sc * 64 + r) * Cz + kq * 4];
    }
    __syncthreads();
    // logits: 4r x 4g per thread, g = lgi + 16j
    {
      float lacc[4][4] = {};
#pragma unroll
      for (int k = 0; k < Dz; k += 4) {
        float4 av[4], bv[4];
#pragma unroll
        for (int i = 0; i < 4; ++i) av[i] = *(float4*)&rows[lr + i][k];
#pragma unroll
        for (int j = 0; j < 4; ++j) bv[j] = *(float4*)&Wst[lgi + 16 * j][k];
#pragma unroll
        for (int i = 0; i < 4; ++i)
#pragma unroll
          for (int j = 0; j < 4; ++j)
            lacc[i][j] += av[i].x * bv[j].x + av[i].y * bv[j].y +
                          av[i].z * bv[j].z + av[i].w * bv[j].w;
      }
#pragma unroll
      for (int i = 0; i < 4; ++i)
#pragma unroll
        for (int j = 0; j < 4; ++j)
          wsm[lr + i][lgi + 16 * j] = (lacc[i][j] + bsl[lgi + 16 * j]) * invt;
    }
    __syncthreads();
    // softmax over g (no max-subtraction: |logit| < ~1.3), 4 threads per row
    {
      float e[16];
      float s = 0.f;
#pragma unroll
      for (int j4 = 0; j4 < 4; ++j4) {
        float4 v = *(float4*)&wsm[sr][sq * 16 + j4 * 4];
        e[j4 * 4 + 0] = __expf(v.x);
        e[j4 * 4 + 1] = __expf(v.y);
        e[j4 * 4 + 2] = __expf(v.z);
        e[j4 * 4 + 3] = __expf(v.w);
        s += e[j4 * 4 + 0] + e[j4 * 4 + 1] + e[j4 * 4 + 2] + e[j4 * 4 + 3];
      }
      s += __shfl_xor(s, 1);
      s += __shfl_xor(s, 2);
      const float inv = 1.0f / s;
#pragma unroll
      for (int j4 = 0; j4 < 4; ++j4) {
        float4 v;
        v.x = e[j4 * 4 + 0] * inv;
        v.y = e[j4 * 4 + 1] * inv;
        v.z = e[j4 * 4 + 2] * inv;
        v.w = e[j4 * 4 + 3] * inv;
        *(float4*)&wsm[sr][sq * 16 + j4 * 4] = v;
      }
    }
    __syncthreads();
    // accumulate: thread owns (4g x 8d), 16 rows slice (rh)
#pragma unroll
    for (int rr = 0; rr < 16; ++rr) {
      const int r = rh * 16 + rr;
      float4 w4 = *(float4*)&wsm[r][g0];
      float4 ra = *(float4*)&rows[r][d0];
      float4 rb = *(float4*)&rows[r][d0 + 4];
      const float wv[4] = {w4.x, w4.y, w4.z, w4.w};
      const float rv[8] = {ra.x, ra.y, ra.z, ra.w, rb.x, rb.y, rb.z, rb.w};
#pragma unroll
      for (int i = 0; i < 4; ++i)
#pragma unroll
        for (int j = 0; j < 8; ++j) pacc[i][j] += wv[i] * rv[j];
      if (dq == 0) {
#pragma unroll
        for (int i = 0; i < 4; ++i) pnorm[i] += wv[i];
      }
    }
  }
  __syncthreads();
#pragma unroll
  for (int i = 0; i < 4; ++i)
#pragma unroll
    for (int j = 0; j < 8; ++j) atomicAdd(&accr[g0 + i][d0 + j], pacc[i][j]);
  if (dq == 0) {
#pragma unroll
    for (int i = 0; i < 4; ++i) atomicAdd(&accn[g0 + i], pnorm[i]);
  }
  __syncthreads();
  for (int i = tid; i < Gz * Dz; i += 256)
    atomicAdd(&accg[(size_t)bh * Gz * Dz + i], ((float*)accr)[i]);
  if (tid < Gz) atomicAdd(&normg[bh * Gz + tid], accn[tid]);
}

// ---------------- tiny per-(b,h) attention over G=64 slice tokens ----------------
__global__ __launch_bounds__(256) void attn_k(
    const float* __restrict__ accg, const float* __restrict__ normg,
    const float* __restrict__ Wq, const float* __restrict__ bq,
    const float* __restrict__ Wk, const float* __restrict__ bk,
    const float* __restrict__ Wv, const float* __restrict__ bv,
    float* __restrict__ osg) {
  __shared__ __align__(16) char pool[50560];
  float(*tok)[36] = (float(*)[36])pool;               // 64x36
  float(*wqs)[36] = (float(*)[36])(pool + 9216);      // 32x36
  float(*wks)[36] = (float(*)[36])(pool + 13824);
  float(*wvs)[36] = (float(*)[36])(pool + 18432);     // ends 23040
  float(*sarr)[68] = (float(*)[68])pool;              // 64x68, aliases tok/wqs/wks (dead then)
  float(*qs)[36] = (float(*)[36])(pool + 23040);
  float(*ks)[36] = (float(*)[36])(pool + 32256);
  float(*vt)[68] = (float(*)[68])(pool + 41472);      // 32x68 (v transposed) ends 50176
  float* bqs = (float*)(pool + 50176);
  float* bks = bqs + 32;
  float* bvs = bks + 32;
  const int tid = threadIdx.x;
  const int bh = blockIdx.x;
  for (int i = tid; i < Gz * Dz; i += 256) {
    int g = i >> 5;
    tok[g][i & 31] = accg[(size_t)bh * 2048 + i] / (normg[bh * 64 + g] + 1e-5f);
  }
  for (int i = tid; i < Dz * Dz; i += 256) {
    int d = i >> 5, j = i & 31;
    wqs[d][j] = Wq[i];
    wks[d][j] = Wk[i];
    wvs[d][j] = Wv[i];
  }
  if (tid < 32) { bqs[tid] = bq[tid]; bks[tid] = bk[tid]; bvs[tid] = bv[tid]; }
  __syncthreads();
  // projections: thread tile 2g x 4j, fused q/k/v
  {
    const int g0 = (tid >> 3) * 2, j0 = (tid & 7) * 4;
    float qa[2][4] = {}, ka[2][4] = {}, va[2][4] = {};
#pragma unroll
    for (int d4 = 0; d4 < Dz; d4 += 4) {
      float4 t0 = *(float4*)&tok[g0][d4];
      float4 t1 = *(float4*)&tok[g0 + 1][d4];
      const float ta[2][4] = {{t0.x, t0.y, t0.z, t0.w}, {t1.x, t1.y, t1.z, t1.w}};
#pragma unroll
      for (int dd = 0; dd < 4; ++dd) {
        float4 wq4 = *(float4*)&wqs[d4 + dd][j0];
        float4 wk4 = *(float4*)&wks[d4 + dd][j0];
        float4 wv4 = *(float4*)&wvs[d4 + dd][j0];
#pragma unroll
        for (int gi = 0; gi < 2; ++gi) {
          qa[gi][0] += ta[gi][dd] * wq4.x;
          qa[gi][1] += ta[gi][dd] * wq4.y;
          qa[gi][2] += ta[gi][dd] * wq4.z;
          qa[gi][3] += ta[gi][dd] * wq4.w;
          ka[gi][0] += ta[gi][dd] * wk4.x;
          ka[gi][1] += ta[gi][dd] * wk4.y;
          ka[gi][2] += ta[gi][dd] * wk4.z;
          ka[gi][3] += ta[gi][dd] * wk4.w;
          va[gi][0] += ta[gi][dd] * wv4.x;
          va[gi][1] += ta[gi][dd] * wv4.y;
          va[gi][2] += ta[gi][dd] * wv4.z;
          va[gi][3] += ta[gi][dd] * wv4.w;
        }
      }
    }
#pragma unroll
    for (int gi = 0; gi < 2; ++gi) {
      float4 oq, ok;
      oq.x = qa[gi][0] + bqs[j0 + 0];
      oq.y = qa[gi][1] + bqs[j0 + 1];
      oq.z = qa[gi][2] + bqs[j0 + 2];
      oq.w = qa[gi][3] + bqs[j0 + 3];
      ok.x = ka[gi][0] + bks[j0 + 0];
      ok.y = ka[gi][1] + bks[j0 + 1];
      ok.z = ka[gi][2] + bks[j0 + 2];
      ok.w = ka[gi][3] + bks[j0 + 3];
      *(float4*)&qs[g0 + gi][j0] = oq;
      *(float4*)&ks[g0 + gi][j0] = ok;
#pragma unroll
      for (int jj = 0; jj < 4; ++jj) vt[j0 + jj][g0 + gi] = va[gi][jj] + bvs[j0 + jj];
    }
  }
  __syncthreads();
  // scores 64x64: thread tile 4i x 4j
  {
    const int i0 = (tid >> 4) * 4, j0 = (tid & 15) * 4;
    float sa[4][4] = {};
#pragma unroll
    for (int d4 = 0; d4 < Dz; d4 += 4) {
      float4 qa4[4], kb4[4];
#pragma unroll
      for (int i = 0; i < 4; ++i) qa4[i] = *(float4*)&qs[i0 + i][d4];
#pragma unroll
      for (int j = 0; j < 4; ++j) kb4[j] = *(float4*)&ks[j0 + j][d4];
#pragma unroll
      for (int i = 0; i < 4; ++i)
#pragma unroll
        for (int j = 0; j < 4; ++j)
          sa[i][j] += qa4[i].x * kb4[j].x + qa4[i].y * kb4[j].y +
                      qa4[i].z * kb4[j].z + qa4[i].w * kb4[j].w;
    }
    const float scale = 0.17677669529663687f;  // 1/sqrt(32)
#pragma unroll
    for (int i = 0; i < 4; ++i) {
      float4 o;
      o.x = sa[i][0] * scale;
      o.y = sa[i][1] * scale;
      o.z = sa[i][2] * scale;
      o.w = sa[i][3] * scale;
      *(float4*)&sarr[i0 + i][j0] = o;
    }
  }
  __syncthreads();
  // softmax rows (no max-subtraction; scores are tiny)
  {
    const int r = tid >> 2, q = tid & 3;
    float e[16];
    float s = 0.f;
#pragma unroll
    for (int j4 = 0; j4 < 4; ++j4) {
      float4 v = *(float4*)&sarr[r][q * 16 + j4 * 4];
      e[j4 * 4 + 0] = __expf(v.x);
      e[j4 * 4 + 1] = __expf(v.y);
      e[j4 * 4 + 2] = __expf(v.z);
      e[j4 * 4 + 3] = __expf(v.w);
      s += e[j4 * 4 + 0] + e[j4 * 4 + 1] + e[j4 * 4 + 2] + e[j4 * 4 + 3];
    }
    s += __shfl_xor(s, 1);
    s += __shfl_xor(s, 2);
    const float inv = 1.0f / s;
#pragma unroll
    for (int j4 = 0; j4 < 4; ++j4) {
      float4 v;
      v.x = e[j4 * 4 + 0] * inv;
      v.y = e[j4 * 4 + 1] * inv;
      v.z = e[j4 * 4 + 2] * inv;
      v.w = e[j4 * 4 + 3] * inv;
      *(float4*)&sarr[r][q * 16 + j4 * 4] = v;
    }
  }
  __syncthreads();
  // out = attn @ v : thread tile 2g x 4d
  {
    const int g0 = (tid >> 3) * 2, d0 = (tid & 7) * 4;
    float oa[2][4] = {};
#pragma unroll
    for (int p4 = 0; p4 < Gz; p4 += 4) {
      float4 a0 = *(float4*)&sarr[g0][p4];
      float4 a1 = *(float4*)&sarr[g0 + 1][p4];
      const float aa[2][4] = {{a0.x, a0.y, a0.z, a0.w}, {a1.x, a1.y, a1.z, a1.w}};
      float4 vv[4];
#pragma unroll
      for (int di = 0; di < 4; ++di) vv[di] = *(float4*)&vt[d0 + di][p4];
#pragma unroll
      for (int gi = 0; gi < 2; ++gi)
#pragma unroll
        for (int di = 0; di < 4; ++di)
          oa[gi][di] += aa[gi][0] * vv[di].x + aa[gi][1] * vv[di].y +
                        aa[gi][2] * vv[di].z + aa[gi][3] * vv[di].w;
    }
#pragma unroll
    for (int gi = 0; gi < 2; ++gi) {
      float4 o;
      o.x = oa[gi][0];
      o.y = oa[gi][1];
      o.z = oa[gi][2];
      o.w = oa[gi][3];
      *(float4*)&osg[(size_t)bh * 2048 + (g0 + gi) * 32 + d0] = o;
    }
  }
}

// ---------------- recompute slice weights + scatter out_small back to points (in-place) --------
__global__ __launch_bounds__(256) void scatter_k(
    float* __restrict__ tmp, const float* __restrict__ Wslice,
    const float* __restrict__ bslice, const float* __restrict__ temp,
    const float* __restrict__ osg) {
  __shared__ __align__(16) float Wst[Gz][36];   // [g][d]
  __shared__ __align__(16) float rows[64][36];  // [r][d]
  __shared__ __align__(16) float wsm[64][68];   // [r][g] logits / weights
  __shared__ __align__(16) float oss[Gz][36];   // [g][d] slice-attention outputs
  __shared__ float bsl[Gz];
  const int tid = threadIdx.x;
  const int bh = blockIdx.x, b = bh >> 3, h = bh & 7;
  for (int i = tid; i < Gz * Dz; i += 256) {
    int d = i >> 6, g = i & 63;
    Wst[g][d] = Wslice[i];
  }
  for (int i = tid; i < Gz * Dz; i += 256) oss[i >> 5][i & 31] = osg[(size_t)bh * 2048 + i];
  if (tid < Gz) bsl[tid] = bslice[tid];
  const float invt = 1.0f / temp[h];
  const size_t base = ((size_t)b * Tz + (size_t)blockIdx.y * 512) * Cz + h * Dz;
  const int lr = (tid >> 4) * 4, lgi = tid & 15;        // interleaved g mapping
  const int sr = tid >> 2, sq = tid & 3;                // softmax: 4 threads / row
  const int orow = (tid >> 3) * 2, od = (tid & 7) * 4;  // output tile 2r x 4d
  for (int sc = 0; sc < 8; ++sc) {
    __syncthreads();
    for (int i = tid; i < 64 * 8; i += 256) {
      int r = i >> 3, kq = i & 7;
      *(float4*)&rows[r][kq * 4] =
          *(const float4*)&tmp[base + (size_t)(sc * 64 + r) * Cz + kq * 4];
    }
    __syncthreads();
    // logits: 4r x 4g per thread, g = lgi + 16j
    {
      float lacc[4][4] = {};
#pragma unroll
      for (int k = 0; k < Dz; k += 4) {
        float4 av[4], bv[4];
#pragma unroll
        for (int i = 0; i < 4; ++i) av[i] = *(float4*)&rows[lr + i][k];
#pragma unroll
        for (int j = 0; j < 4; ++j) bv[j] = *(float4*)&Wst[lgi + 16 * j][k];
#pragma unroll
        for (int i = 0; i < 4; ++i)
#pragma unroll
          for (int j = 0; j < 4; ++j)
            lacc[i][j] += av[i].x * bv[j].x + av[i].y * bv[j].y +
                          av[i].z * bv[j].z + av[i].w * bv[j].w;
      }
#pragma unroll
      for (int i = 0; i < 4; ++i)
#pragma unroll
        for (int j = 0; j < 4; ++j)
          wsm[lr + i][lgi + 16 * j] = (lacc[i][j] + bsl[lgi + 16 * j]) * invt;
    }
    __syncthreads();
    // softmax over g, normalized weights written back to wsm
    {
      float e[16];
      float s = 0.f;
#pragma unroll
      for (int j4 = 0; j4 < 4; ++j4) {
        float4 v = *(float4*)&wsm[sr][sq * 16 + j4 * 4];
        e[j4 * 4 + 0] = __expf(v.x);
        e[j4 * 4 + 1] = __expf(v.y);
        e[j4 * 4 + 2] = __expf(v.z);
        e[j4 * 4 + 3] = __expf(v.w);
        s += e[j4 * 4 + 0] + e[j4 * 4 + 1] + e[j4 * 4 + 2] + e[j4 * 4 + 3];
      }
      s += __shfl_xor(s, 1);
      s += __shfl_xor(s, 2);
      const float inv = 1.0f / s;
#pragma unroll
      for (int j4 = 0; j4 < 4; ++j4) {
        float4 v;
        v.x = e[j4 * 4 + 0] * inv;
        v.y = e[j4 * 4 + 1] * inv;
        v.z = e[j4 * 4 + 2] * inv;
        v.w = e[j4 * 4 + 3] * inv;
        *(float4*)&wsm[sr][sq * 16 + j4 * 4] = v;
      }
    }
    __syncthreads();
    // out = wsm @ oss : thread tile 2r x 4d, g-steps of 4 (all static indexing)
    {
      float oa[2][4] = {};
#pragma unroll
      for (int g = 0; g < Gz; g += 4) {
        float4 w0 = *(float4*)&wsm[orow][g];
        float4 w1 = *(float4*)&wsm[orow + 1][g];
        float4 v0 = *(float4*)&oss[g + 0][od];
        float4 v1 = *(float4*)&oss[g + 1][od];
        float4 v2 = *(float4*)&oss[g + 2][od];
        float4 v3 = *(float4*)&oss[g + 3][od];
        oa[0][0] += w0.x * v0.x + w0.y * v1.x + w0.z * v2.x + w0.w * v3.x;
        oa[0][1] += w0.x * v0.y + w0.y * v1.y + w0.z * v2.y + w0.w * v3.y;
        oa[0][2] += w0.x * v0.z + w0.y * v1.z + w0.z * v2.z + w0.w * v3.z;
        oa[0][3] += w0.x * v0.w + w0.y * v1.w + w0.z * v2.w + w0.w * v3.w;
        oa[1][0] += w1.x * v0.x + w1.y * v1.x + w1.z * v2.x + w1.w * v3.x;
        oa[1][1] += w1.x * v0.y + w1.y * v1.y + w1.z * v2.y + w1.w * v3.y;
        oa[1][2] += w1.x * v0.z + w1.y * v1.z + w1.z * v2.z + w1.w * v3.z;
        oa[1][3] += w1.x * v0.w + w1.y * v1.w + w1.z * v2.w + w1.w * v3.w;
      }
#pragma unroll
      for (int gi = 0; gi < 2; ++gi) {
        float4 o;
        o.x = oa[gi][0];
        o.y = oa[gi][1];
        o.z = oa[gi][2];
        o.w = oa[gi][3];
        *(float4*)&tmp[base + (size_t)(sc * 64 + orow + gi) * Cz + od] = o;
      }
    }
  }
}

extern "C" void kernel_launch(void* const* d_in, const int* in_sizes, int n_in,
                              void* d_out, int out_size, void* d_ws, size_t ws_size,
                              hipStream_t stream) {
  (void)in_sizes; (void)n_in; (void)out_size;
  const float* x_q = (const float*)d_in[0];
  const float* W_in = (const float*)d_in[3];
  const float* b_in = (const float*)d_in[4];
  const float* W_slice = (const float*)d_in[5];
  const float* b_slice = (const float*)d_in[6];
  const float* temperature = (const float*)d_in[7];
  const float* W_q = (const float*)d_in[8];
  const float* b_q = (const float*)d_in[9];
  const float* W_k = (const float*)d_in[10];
  const float* b_k = (const float*)d_in[11];
  const float* W_v = (const float*)d_in[12];
  const float* b_v = (const float*)d_in[13];
  const float* W_out = (const float*)d_in[14];
  const float* b_out = (const float*)d_in[15];
  float* out = (float*)d_out;

  const size_t tmp_elems = (size_t)Bz * Tz * Cz;       // 16,777,216
  const size_t acc_elems = (size_t)Bz * Hz * Gz * Dz;  // 131,072
  const size_t norm_elems = (size_t)Bz * Hz * Gz;      // 4,096
  const size_t small_elems = acc_elems + norm_elems + acc_elems;
  const size_t wt_bytes = 4 * (size_t)Cz * Cz * sizeof(unsigned short);  // 512 KB
  const bool ws_big = ws_size >= (tmp_elems + small_elems) * sizeof(float) + wt_bytes;

  float* tmp;
  float* accg;
  if (ws_big) {
    tmp = (float*)d_ws;
    accg = tmp + tmp_elems;
  } else {
    tmp = out;  // fall back: big intermediate lives in d_out; final GEMM runs in-place
    accg = (float*)d_ws;
  }
  float* normg = accg + acc_elems;
  float* osg = normg + norm_elems;
  unsigned short* winh = (unsigned short*)(osg + acc_elems);
  unsigned short* winl = winh + Cz * Cz;
  unsigned short* wouth = winl + Cz * Cz;
  unsigned short* woutl = wouth + Cz * Cz;

  hipMemsetAsync(accg, 0, (acc_elems + norm_elems) * sizeof(float), stream);

  prep_k<<<Cz, Cz, 0, stream>>>(W_in, W_out, winh, winl, wouth, woutl);
  gemm_mfma<<<dim3(Bz * Tz / 128, 2), 256, 0, stream>>>(x_q, winh, winl, b_in, tmp);
  pool_k<<<dim3(Bz * Hz, Tz / 512), 256, 0, stream>>>(tmp, W_slice, b_slice, temperature,
                                                      accg, normg);
  attn_k<<<Bz * Hz, 256, 0, stream>>>(accg, normg, W_q, b_q, W_k, b_k, W_v, b_v, osg);
  scatter_k<<<dim3(Bz * Hz, Tz / 512), 256, 0, stream>>>(tmp, W_slice, b_slice, temperature,
                                                         osg);
  // In-place safe: each block reads only its own 128 rows before writing them.
  gemm_mfma<<<dim3(Bz * Tz / 128, 2), 256, 0, stream>>>(tmp, wouth, woutl, b_out, out);
}

// Round 4
// 343.881 us; speedup vs baseline: 17.2271x; 1.4436x over previous
//
#include <hip/hip_runtime.h>

#define Bz 8
#define Tz 8192
#define Cz 256
#define Hz 8
#define Gz 64
#define Dz 32

typedef __bf16 bf16x8 __attribute__((ext_vector_type(8)));
typedef float f32x4 __attribute__((ext_vector_type(4)));

#define MFMA(a, b, c) __builtin_amdgcn_mfma_f32_16x16x32_bf16((a), (b), (c), 0, 0, 0)

__device__ inline void splitbf(float x, unsigned short& h, unsigned short& l) {
  __bf16 hb = (__bf16)x;
  float r = x - (float)hb;
  __bf16 lb = (__bf16)r;
  h = __builtin_bit_cast(unsigned short, hb);
  l = __builtin_bit_cast(unsigned short, lb);
}
__device__ inline __bf16 us2bf(unsigned short u) { return __builtin_bit_cast(__bf16, u); }

// ---------------- prep: split W (K x N) into bf16 hi/lo, transposed to [n][k] ----------------
__global__ __launch_bounds__(256) void prep_k(
    const float* __restrict__ Win, const float* __restrict__ Wout,
    unsigned short* __restrict__ winh, unsigned short* __restrict__ winl,
    unsigned short* __restrict__ wouth, unsigned short* __restrict__ woutl) {
  const int k = blockIdx.x, n = threadIdx.x;
  unsigned short h, l;
  splitbf(Win[k * Cz + n], h, l);
  winh[n * Cz + k] = h;
  winl[n * Cz + k] = l;
  splitbf(Wout[k * Cz + n], h, l);
  wouth[n * Cz + k] = h;
  woutl[n * Cz + k] = l;
}

// ---------------- split-bf16 MFMA GEMM: Y = X @ W + bias (W pre-split as Wt[n][k]) ----------
__global__ __launch_bounds__(256, 3) void gemm_mfma(
    const float* __restrict__ X, const unsigned short* __restrict__ Wh,
    const unsigned short* __restrict__ Wl, const float* __restrict__ bias, float* Y) {
  __shared__ __align__(16) unsigned short Ah[128][40];
  __shared__ __align__(16) unsigned short Al[128][40];
  __shared__ __align__(16) unsigned short Bth[128][40];
  __shared__ __align__(16) unsigned short Btl[128][40];
  const int tid = threadIdx.x;
  const size_t m0 = (size_t)blockIdx.x * 128;
  const int n0 = blockIdx.y * 128;
  const int lane = tid & 63, wave = tid >> 6;
  const int lm = lane & 15, quad = lane >> 4, k8 = quad * 8;
  const int wm = (wave & 1) * 64, wn = (wave >> 1) * 64;
  f32x4 acc[4][4] = {};
  for (int kt = 0; kt < Cz; kt += 32) {
    __syncthreads();
#pragma unroll
    for (int u = 0; u < 4; ++u) {
      int idx = tid + u * 256;
      int row = idx >> 3, q = idx & 7;
      float4 v = *(const float4*)&X[(m0 + row) * Cz + kt + q * 4];
      unsigned short h0, l0, h1, l1, h2, l2, h3, l3;
      splitbf(v.x, h0, l0);
      splitbf(v.y, h1, l1);
      splitbf(v.z, h2, l2);
      splitbf(v.w, h3, l3);
      ushort4 hv = {h0, h1, h2, h3};
      ushort4 lv = {l0, l1, l2, l3};
      *(ushort4*)&Ah[row][q * 4] = hv;
      *(ushort4*)&Al[row][q * 4] = lv;
    }
#pragma unroll
    for (int u = 0; u < 2; ++u) {
      int idx = tid + u * 256;
      int row = idx >> 2, q = idx & 3;
      uint4 hv = *(const uint4*)&Wh[(size_t)(n0 + row) * Cz + kt + q * 8];
      uint4 lv = *(const uint4*)&Wl[(size_t)(n0 + row) * Cz + kt + q * 8];
      *(uint4*)&Bth[row][q * 8] = hv;
      *(uint4*)&Btl[row][q * 8] = lv;
    }
    __syncthreads();
    bf16x8 bh[4], bl[4];
#pragma unroll
    for (int nt = 0; nt < 4; ++nt) {
      bh[nt] = *(const bf16x8*)&Bth[wn + nt * 16 + lm][k8];
      bl[nt] = *(const bf16x8*)&Btl[wn + nt * 16 + lm][k8];
    }
#pragma unroll
    for (int mt = 0; mt < 4; ++mt) {
      bf16x8 ah = *(const bf16x8*)&Ah[wm + mt * 16 + lm][k8];
      bf16x8 alo = *(const bf16x8*)&Al[wm + mt * 16 + lm][k8];
#pragma unroll
      for (int nt = 0; nt < 4; ++nt) {
        acc[mt][nt] = MFMA(alo, bh[nt], acc[mt][nt]);
        acc[mt][nt] = MFMA(ah, bl[nt], acc[mt][nt]);
        acc[mt][nt] = MFMA(ah, bh[nt], acc[mt][nt]);
      }
    }
  }
  float bcol[4];
#pragma unroll
  for (int nt = 0; nt < 4; ++nt) bcol[nt] = bias[n0 + wn + nt * 16 + lm];
#pragma unroll
  for (int mt = 0; mt < 4; ++mt)
#pragma unroll
    for (int nt = 0; nt < 4; ++nt)
#pragma unroll
      for (int r = 0; r < 4; ++r) {
        size_t row = m0 + wm + mt * 16 + quad * 4 + r;
        Y[row * Cz + n0 + wn + nt * 16 + lm] = acc[mt][nt][r] + bcol[nt];
      }
}

// ---------------- pool: logits (MFMA) -> softmax -> pooled tokens (MFMA) ----------------
// Writes accgT[bh][d][g] (transposed) and normg[bh][g] via atomics.
__global__ __launch_bounds__(256) void pool_k(
    const float* __restrict__ tmp, const float* __restrict__ Wslice,
    const float* __restrict__ bslice, const float* __restrict__ temp,
    float* __restrict__ accgT, float* __restrict__ normg) {
  __shared__ __align__(16) unsigned short rowsH[64][40];  // [r][d]
  __shared__ __align__(16) unsigned short rowsL[64][40];
  __shared__ __align__(16) unsigned short rowTH[32][72];  // [d][r]
  __shared__ __align__(16) unsigned short rowTL[32][72];
  __shared__ __align__(16) unsigned short wTH[64][72];    // [g][r]
  __shared__ __align__(16) unsigned short wTL[64][72];
  __shared__ float accn[Gz];
  const int tid = threadIdx.x;
  const int bh = blockIdx.x, b = bh >> 3, h = bh & 7;
  const int lane = tid & 63, wave = tid >> 6;
  const int lm = lane & 15, quad = lane >> 4, k8 = quad * 8;
  if (tid < Gz) accn[tid] = 0.f;
  const float invt = 1.0f / temp[h];
  // Wst A-frags (M=g, K=d): lane holds Wst[g=16mt+lm][d=k8+j] = Wslice[(k8+j)*G + g]
  bf16x8 wsh[4], wsl[4];
#pragma unroll
  for (int mt = 0; mt < 4; ++mt)
#pragma unroll
    for (int j = 0; j < 8; ++j) {
      unsigned short hh, ll;
      splitbf(Wslice[(k8 + j) * Gz + mt * 16 + lm], hh, ll);
      wsh[mt][j] = us2bf(hh);
      wsl[mt][j] = us2bf(ll);
    }
  float bsv[4][4];
#pragma unroll
  for (int mt = 0; mt < 4; ++mt)
#pragma unroll
    for (int r = 0; r < 4; ++r) bsv[mt][r] = bslice[mt * 16 + quad * 4 + r];
  f32x4 pacc[2] = {};  // accT frags: d-tile md, g-tiles ngb..ngb+1
  float pn[4][4] = {};
  const int md = wave & 1, ngb = (wave >> 1) * 2;
  const size_t base = ((size_t)b * Tz + (size_t)blockIdx.y * 512) * Cz + h * Dz;
  const int strow = tid >> 2, stq = tid & 3;
  for (int sc = 0; sc < 8; ++sc) {
    __syncthreads();
    {  // stage 64 rows -> rows (r-major) and rowT (d-major), bf16 hi/lo
      const float* src = &tmp[base + (size_t)(sc * 64 + strow) * Cz + stq * 8];
      float4 va = *(const float4*)src;
      float4 vb = *(const float4*)(src + 4);
      unsigned short hs[8], ls[8];
      splitbf(va.x, hs[0], ls[0]);
      splitbf(va.y, hs[1], ls[1]);
      splitbf(va.z, hs[2], ls[2]);
      splitbf(va.w, hs[3], ls[3]);
      splitbf(vb.x, hs[4], ls[4]);
      splitbf(vb.y, hs[5], ls[5]);
      splitbf(vb.z, hs[6], ls[6]);
      splitbf(vb.w, hs[7], ls[7]);
      ushort4 ha = {hs[0], hs[1], hs[2], hs[3]}, hb = {hs[4], hs[5], hs[6], hs[7]};
      ushort4 la = {ls[0], ls[1], ls[2], ls[3]}, lb = {ls[4], ls[5], ls[6], ls[7]};
      *(ushort4*)&rowsH[strow][stq * 8] = ha;
      *(ushort4*)&rowsH[strow][stq * 8 + 4] = hb;
      *(ushort4*)&rowsL[strow][stq * 8] = la;
      *(ushort4*)&rowsL[strow][stq * 8 + 4] = lb;
#pragma unroll
      for (int j = 0; j < 8; ++j) {
        rowTH[stq * 8 + j][strow] = hs[j];
        rowTL[stq * 8 + j][strow] = ls[j];
      }
    }
    __syncthreads();
    // logits ST[g][r] = Wst @ rowsT: wave owns r-tile `wave`; B-frag = rows[r][d contiguous]
    bf16x8 rh = *(const bf16x8*)&rowsH[wave * 16 + lm][k8];
    bf16x8 rl = *(const bf16x8*)&rowsL[wave * 16 + lm][k8];
    float ev[4][4];
    float s = 0.f;
#pragma unroll
    for (int mt = 0; mt < 4; ++mt) {
      f32x4 st = {};
      st = MFMA(wsl[mt], rh, st);
      st = MFMA(wsh[mt], rl, st);
      st = MFMA(wsh[mt], rh, st);
#pragma unroll
      for (int r = 0; r < 4; ++r) {
        float e = __expf((st[r] + bsv[mt][r]) * invt);
        ev[mt][r] = e;
        s += e;
      }
    }
    s += __shfl_xor(s, 16);
    s += __shfl_xor(s, 32);
    const float inv = 1.0f / s;
#pragma unroll
    for (int mt = 0; mt < 4; ++mt)
#pragma unroll
      for (int r = 0; r < 4; ++r) {
        float w = ev[mt][r] * inv;
        pn[mt][r] += w;
        unsigned short hh, ll;
        splitbf(w, hh, ll);
        wTH[mt * 16 + quad * 4 + r][wave * 16 + lm] = hh;
        wTL[mt * 16 + quad * 4 + r][wave * 16 + lm] = ll;
      }
    __syncthreads();
    // pooling accT[d][g] += rowsT(d x r) @ w(r x g); B[r][g] = wT[g][r] contiguous in r
#pragma unroll
    for (int ks = 0; ks < 2; ++ks) {
      bf16x8 ah = *(const bf16x8*)&rowTH[md * 16 + lm][ks * 32 + k8];
      bf16x8 al = *(const bf16x8*)&rowTL[md * 16 + lm][ks * 32 + k8];
#pragma unroll
      for (int nt = 0; nt < 2; ++nt) {
        bf16x8 bh = *(const bf16x8*)&wTH[(ngb + nt) * 16 + lm][ks * 32 + k8];
        bf16x8 bl = *(const bf16x8*)&wTL[(ngb + nt) * 16 + lm][ks * 32 + k8];
        pacc[nt] = MFMA(al, bh, pacc[nt]);
        pacc[nt] = MFMA(ah, bl, pacc[nt]);
        pacc[nt] = MFMA(ah, bh, pacc[nt]);
      }
    }
  }
  // norms: reduce pn over the wave's 16 r's, then LDS, then global
#pragma unroll
  for (int mt = 0; mt < 4; ++mt)
#pragma unroll
    for (int r = 0; r < 4; ++r) {
      float v = pn[mt][r];
      v += __shfl_xor(v, 1);
      v += __shfl_xor(v, 2);
      v += __shfl_xor(v, 4);
      v += __shfl_xor(v, 8);
      if (lm == 0) atomicAdd(&accn[mt * 16 + quad * 4 + r], v);
    }
  __syncthreads();
  if (tid < Gz) atomicAdd(&normg[bh * Gz + tid], accn[tid]);
#pragma unroll
  for (int nt = 0; nt < 2; ++nt)
#pragma unroll
    for (int r = 0; r < 4; ++r) {
      int d = md * 16 + quad * 4 + r;
      int g = (ngb + nt) * 16 + lm;
      atomicAdd(&accgT[(size_t)bh * 2048 + d * Gz + g], pacc[nt][r]);
    }
}

// ---------------- tiny per-(b,h) attention over G=64 slice tokens ----------------
__global__ __launch_bounds__(256) void attn_k(
    const float* __restrict__ accgT, const float* __restrict__ normg,
    const float* __restrict__ Wq, const float* __restrict__ bq,
    const float* __restrict__ Wk, const float* __restrict__ bk,
    const float* __restrict__ Wv, const float* __restrict__ bv,
    float* __restrict__ osg) {
  __shared__ __align__(16) char pool[50560];
  float(*tok)[36] = (float(*)[36])pool;            // 64x36
  float(*wqs)[36] = (float(*)[36])(pool + 9216);   // 32x36
  float(*wks)[36] = (float(*)[36])(pool + 13824);
  float(*wvs)[36] = (float(*)[36])(pool + 18432);  // ends 23040
  float(*sarr)[68] = (float(*)[68])pool;           // 64x68, aliases tok/wqs/wks (dead then)
  float(*qs)[36] = (float(*)[36])(pool + 23040);
  float(*ks)[36] = (float(*)[36])(pool + 32256);
  float(*vt)[68] = (float(*)[68])(pool + 41472);   // 32x68 (v transposed) ends 50176
  float* bqs = (float*)(pool + 50176);
  float* bks = bqs + 32;
  float* bvs = bks + 32;
  const int tid = threadIdx.x;
  const int bh = blockIdx.x;
  for (int i = tid; i < Gz * Dz; i += 256) {
    int d = i >> 6, g = i & 63;  // accgT is [d][g]
    tok[g][d] = accgT[(size_t)bh * 2048 + i] / (normg[bh * 64 + g] + 1e-5f);
  }
  for (int i = tid; i < Dz * Dz; i += 256) {
    int d = i >> 5, j = i & 31;
    wqs[d][j] = Wq[i];
    wks[d][j] = Wk[i];
    wvs[d][j] = Wv[i];
  }
  if (tid < 32) { bqs[tid] = bq[tid]; bks[tid] = bk[tid]; bvs[tid] = bv[tid]; }
  __syncthreads();
  {
    const int g0 = (tid >> 3) * 2, j0 = (tid & 7) * 4;
    float qa[2][4] = {}, ka[2][4] = {}, va[2][4] = {};
#pragma unroll
    for (int d4 = 0; d4 < Dz; d4 += 4) {
      float4 t0 = *(float4*)&tok[g0][d4];
      float4 t1 = *(float4*)&tok[g0 + 1][d4];
      const float ta[2][4] = {{t0.x, t0.y, t0.z, t0.w}, {t1.x, t1.y, t1.z, t1.w}};
#pragma unroll
      for (int dd = 0; dd < 4; ++dd) {
        float4 wq4 = *(float4*)&wqs[d4 + dd][j0];
        float4 wk4 = *(float4*)&wks[d4 + dd][j0];
        float4 wv4 = *(float4*)&wvs[d4 + dd][j0];
#pragma unroll
        for (int gi = 0; gi < 2; ++gi) {
          qa[gi][0] += ta[gi][dd] * wq4.x;
          qa[gi][1] += ta[gi][dd] * wq4.y;
          qa[gi][2] += ta[gi][dd] * wq4.z;
          qa[gi][3] += ta[gi][dd] * wq4.w;
          ka[gi][0] += ta[gi][dd] * wk4.x;
          ka[gi][1] += ta[gi][dd] * wk4.y;
          ka[gi][2] += ta[gi][dd] * wk4.z;
          ka[gi][3] += ta[gi][dd] * wk4.w;
          va[gi][0] += ta[gi][dd] * wv4.x;
          va[gi][1] += ta[gi][dd] * wv4.y;
          va[gi][2] += ta[gi][dd] * wv4.z;
          va[gi][3] += ta[gi][dd] * wv4.w;
        }
      }
    }
#pragma unroll
    for (int gi = 0; gi < 2; ++gi) {
      float4 oq, ok;
      oq.x = qa[gi][0] + bqs[j0 + 0];
      oq.y = qa[gi][1] + bqs[j0 + 1];
      oq.z = qa[gi][2] + bqs[j0 + 2];
      oq.w = qa[gi][3] + bqs[j0 + 3];
      ok.x = ka[gi][0] + bks[j0 + 0];
      ok.y = ka[gi][1] + bks[j0 + 1];
      ok.z = ka[gi][2] + bks[j0 + 2];
      ok.w = ka[gi][3] + bks[j0 + 3];
      *(float4*)&qs[g0 + gi][j0] = oq;
      *(float4*)&ks[g0 + gi][j0] = ok;
#pragma unroll
      for (int jj = 0; jj < 4; ++jj) vt[j0 + jj][g0 + gi] = va[gi][jj] + bvs[j0 + jj];
    }
  }
  __syncthreads();
  {
    const int i0 = (tid >> 4) * 4, j0 = (tid & 15) * 4;
    float sa[4][4] = {};
#pragma unroll
    for (int d4 = 0; d4 < Dz; d4 += 4) {
      float4 qa4[4], kb4[4];
#pragma unroll
      for (int i = 0; i < 4; ++i) qa4[i] = *(float4*)&qs[i0 + i][d4];
#pragma unroll
      for (int j = 0; j < 4; ++j) kb4[j] = *(float4*)&ks[j0 + j][d4];
#pragma unroll
      for (int i = 0; i < 4; ++i)
#pragma unroll
        for (int j = 0; j < 4; ++j)
          sa[i][j] += qa4[i].x * kb4[j].x + qa4[i].y * kb4[j].y +
                      qa4[i].z * kb4[j].z + qa4[i].w * kb4[j].w;
    }
    const float scale = 0.17677669529663687f;
#pragma unroll
    for (int i = 0; i < 4; ++i) {
      float4 o;
      o.x = sa[i][0] * scale;
      o.y = sa[i][1] * scale;
      o.z = sa[i][2] * scale;
      o.w = sa[i][3] * scale;
      *(float4*)&sarr[i0 + i][j0] = o;
    }
  }
  __syncthreads();
  {
    const int r = tid >> 2, q = tid & 3;
    float e[16];
    float s = 0.f;
#pragma unroll
    for (int j4 = 0; j4 < 4; ++j4) {
      float4 v = *(float4*)&sarr[r][q * 16 + j4 * 4];
      e[j4 * 4 + 0] = __expf(v.x);
      e[j4 * 4 + 1] = __expf(v.y);
      e[j4 * 4 + 2] = __expf(v.z);
      e[j4 * 4 + 3] = __expf(v.w);
      s += e[j4 * 4 + 0] + e[j4 * 4 + 1] + e[j4 * 4 + 2] + e[j4 * 4 + 3];
    }
    s += __shfl_xor(s, 1);
    s += __shfl_xor(s, 2);
    const float inv = 1.0f / s;
#pragma unroll
    for (int j4 = 0; j4 < 4; ++j4) {
      float4 v;
      v.x = e[j4 * 4 + 0] * inv;
      v.y = e[j4 * 4 + 1] * inv;
      v.z = e[j4 * 4 + 2] * inv;
      v.w = e[j4 * 4 + 3] * inv;
      *(float4*)&sarr[r][q * 16 + j4 * 4] = v;
    }
  }
  __syncthreads();
  {
    const int g0 = (tid >> 3) * 2, d0 = (tid & 7) * 4;
    float oa[2][4] = {};
#pragma unroll
    for (int p4 = 0; p4 < Gz; p4 += 4) {
      float4 a0 = *(float4*)&sarr[g0][p4];
      float4 a1 = *(float4*)&sarr[g0 + 1][p4];
      const float aa[2][4] = {{a0.x, a0.y, a0.z, a0.w}, {a1.x, a1.y, a1.z, a1.w}};
      float4 vv[4];
#pragma unroll
      for (int di = 0; di < 4; ++di) vv[di] = *(float4*)&vt[d0 + di][p4];
#pragma unroll
      for (int gi = 0; gi < 2; ++gi)
#pragma unroll
        for (int di = 0; di < 4; ++di)
          oa[gi][di] += aa[gi][0] * vv[di].x + aa[gi][1] * vv[di].y +
                        aa[gi][2] * vv[di].z + aa[gi][3] * vv[di].w;
    }
#pragma unroll
    for (int gi = 0; gi < 2; ++gi) {
      float4 o;
      o.x = oa[gi][0];
      o.y = oa[gi][1];
      o.z = oa[gi][2];
      o.w = oa[gi][3];
      *(float4*)&osg[(size_t)bh * 2048 + (g0 + gi) * 32 + d0] = o;
    }
  }
}

// ---------------- scatter: logits (MFMA) -> softmax -> out = w @ oss (MFMA), in-place -----
__global__ __launch_bounds__(256) void scatter_k(
    float* __restrict__ tmp, const float* __restrict__ Wslice,
    const float* __restrict__ bslice, const float* __restrict__ temp,
    const float* __restrict__ osg) {
  __shared__ __align__(16) unsigned short rowsH[64][40];   // [r][d]
  __shared__ __align__(16) unsigned short rowsL[64][40];
  __shared__ __align__(16) unsigned short wH[64][72];      // [r][g]
  __shared__ __align__(16) unsigned short wL[64][72];
  __shared__ __align__(16) unsigned short ossTH[32][72];   // [d][g]
  __shared__ __align__(16) unsigned short ossTL[32][72];
  const int tid = threadIdx.x;
  const int bh = blockIdx.x, b = bh >> 3, h = bh & 7;
  const int lane = tid & 63, wave = tid >> 6;
  const int lm = lane & 15, quad = lane >> 4, k8 = quad * 8;
  // stage ossT
  for (int i = tid; i < Gz * Dz; i += 256) {
    int g = i >> 5, d = i & 31;
    unsigned short hh, ll;
    splitbf(osg[(size_t)bh * 2048 + i], hh, ll);
    ossTH[d][g] = hh;
    ossTL[d][g] = ll;
  }
  const float invt = 1.0f / temp[h];
  // Wst B-frags (K=d, N=g): lane holds Wst[g=16nt+lm][d=k8+j]
  bf16x8 wsh[4], wsl[4];
#pragma unroll
  for (int nt = 0; nt < 4; ++nt)
#pragma unroll
    for (int j = 0; j < 8; ++j) {
      unsigned short hh, ll;
      splitbf(Wslice[(k8 + j) * Gz + nt * 16 + lm], hh, ll);
      wsh[nt][j] = us2bf(hh);
      wsl[nt][j] = us2bf(ll);
    }
  float bsv[4];
#pragma unroll
  for (int nt = 0; nt < 4; ++nt) bsv[nt] = bslice[nt * 16 + lm];
  __syncthreads();
  // preload oss B-frags (B[k=g][n=d] = ossT[d][g] contiguous in g)
  bf16x8 obh[2][2], obl[2][2];  // [nt2][ks]
#pragma unroll
  for (int nt2 = 0; nt2 < 2; ++nt2)
#pragma unroll
    for (int ksi = 0; ksi < 2; ++ksi) {
      obh[nt2][ksi] = *(const bf16x8*)&ossTH[nt2 * 16 + lm][ksi * 32 + k8];
      obl[nt2][ksi] = *(const bf16x8*)&ossTL[nt2 * 16 + lm][ksi * 32 + k8];
    }
  const size_t base = ((size_t)b * Tz + (size_t)blockIdx.y * 512) * Cz + h * Dz;
  const int strow = tid >> 2, stq = tid & 3;
  for (int sc = 0; sc < 8; ++sc) {
    __syncthreads();
    {  // stage 64 rows (r-major only)
      const float* src = &tmp[base + (size_t)(sc * 64 + strow) * Cz + stq * 8];
      float4 va = *(const float4*)src;
      float4 vb = *(const float4*)(src + 4);
      unsigned short hs[8], ls[8];
      splitbf(va.x, hs[0], ls[0]);
      splitbf(va.y, hs[1], ls[1]);
      splitbf(va.z, hs[2], ls[2]);
      splitbf(va.w, hs[3], ls[3]);
      splitbf(vb.x, hs[4], ls[4]);
      splitbf(vb.y, hs[5], ls[5]);
      splitbf(vb.z, hs[6], ls[6]);
      splitbf(vb.w, hs[7], ls[7]);
      ushort4 ha = {hs[0], hs[1], hs[2], hs[3]}, hb = {hs[4], hs[5], hs[6], hs[7]};
      ushort4 la = {ls[0], ls[1], ls[2], ls[3]}, lb = {ls[4], ls[5], ls[6], ls[7]};
      *(ushort4*)&rowsH[strow][stq * 8] = ha;
      *(ushort4*)&rowsH[strow][stq * 8 + 4] = hb;
      *(ushort4*)&rowsL[strow][stq * 8] = la;
      *(ushort4*)&rowsL[strow][stq * 8 + 4] = lb;
    }
    __syncthreads();
    // logits S[r][g] = rows @ WstT: wave owns r-tile `wave`
    bf16x8 rh = *(const bf16x8*)&rowsH[wave * 16 + lm][k8];
    bf16x8 rl = *(const bf16x8*)&rowsL[wave * 16 + lm][k8];
    float ev[4][4];
    float sreg[4] = {0.f, 0.f, 0.f, 0.f};
#pragma unroll
    for (int nt = 0; nt < 4; ++nt) {
      f32x4 st = {};
      st = MFMA(rl, wsh[nt], st);
      st = MFMA(rh, wsl[nt], st);
      st = MFMA(rh, wsh[nt], st);
#pragma unroll
      for (int r = 0; r < 4; ++r) {
        float e = __expf((st[r] + bsv[nt]) * invt);
        ev[nt][r] = e;
        sreg[r] += e;
      }
    }
#pragma unroll
    for (int r = 0; r < 4; ++r) {
      sreg[r] += __shfl_xor(sreg[r], 1);
      sreg[r] += __shfl_xor(sreg[r], 2);
      sreg[r] += __shfl_xor(sreg[r], 4);
      sreg[r] += __shfl_xor(sreg[r], 8);
      sreg[r] = 1.0f / sreg[r];
    }
#pragma unroll
    for (int nt = 0; nt < 4; ++nt)
#pragma unroll
      for (int r = 0; r < 4; ++r) {
        float w = ev[nt][r] * sreg[r];
        unsigned short hh, ll;
        splitbf(w, hh, ll);
        wH[wave * 16 + quad * 4 + r][nt * 16 + lm] = hh;
        wL[wave * 16 + quad * 4 + r][nt * 16 + lm] = ll;
      }
    __syncthreads();
    // out[r][d] = w(r x g) @ oss(g x d): A = w rows (contiguous g), B preloaded
    f32x4 oacc[2] = {};
#pragma unroll
    for (int ksi = 0; ksi < 2; ++ksi) {
      bf16x8 ah = *(const bf16x8*)&wH[wave * 16 + lm][ksi * 32 + k8];
      bf16x8 al = *(const bf16x8*)&wL[wave * 16 + lm][ksi * 32 + k8];
#pragma unroll
      for (int nt2 = 0; nt2 < 2; ++nt2) {
        oacc[nt2] = MFMA(al, obh[nt2][ksi], oacc[nt2]);
        oacc[nt2] = MFMA(ah, obl[nt2][ksi], oacc[nt2]);
        oacc[nt2] = MFMA(ah, obh[nt2][ksi], oacc[nt2]);
      }
    }
#pragma unroll
    for (int nt2 = 0; nt2 < 2; ++nt2)
#pragma unroll
      for (int r = 0; r < 4; ++r) {
        tmp[base + (size_t)(sc * 64 + wave * 16 + quad * 4 + r) * Cz + nt2 * 16 + lm] =
            oacc[nt2][r];
      }
  }
}

extern "C" void kernel_launch(void* const* d_in, const int* in_sizes, int n_in,
                              void* d_out, int out_size, void* d_ws, size_t ws_size,
                              hipStream_t stream) {
  (void)in_sizes; (void)n_in; (void)out_size;
  const float* x_q = (const float*)d_in[0];
  const float* W_in = (const float*)d_in[3];
  const float* b_in = (const float*)d_in[4];
  const float* W_slice = (const float*)d_in[5];
  const float* b_slice = (const float*)d_in[6];
  const float* temperature = (const float*)d_in[7];
  const float* W_q = (const float*)d_in[8];
  const float* b_q = (const float*)d_in[9];
  const float* W_k = (const float*)d_in[10];
  const float* b_k = (const float*)d_in[11];
  const float* W_v = (const float*)d_in[12];
  const float* b_v = (const float*)d_in[13];
  const float* W_out = (const float*)d_in[14];
  const float* b_out = (const float*)d_in[15];
  float* out = (float*)d_out;

  const size_t tmp_elems = (size_t)Bz * Tz * Cz;
  const size_t acc_elems = (size_t)Bz * Hz * Gz * Dz;
  const size_t norm_elems = (size_t)Bz * Hz * Gz;
  const size_t small_elems = acc_elems + norm_elems + acc_elems;
  const size_t wt_bytes = 4 * (size_t)Cz * Cz * sizeof(unsigned short);
  const bool ws_big = ws_size >= (tmp_elems + small_elems) * sizeof(float) + wt_bytes;

  float* tmp;
  float* accgT;
  if (ws_big) {
    tmp = (float*)d_ws;
    accgT = tmp + tmp_elems;
  } else {
    tmp = out;
    accgT = (float*)d_ws;
  }
  float* normg = accgT + acc_elems;
  float* osg = normg + norm_elems;
  unsigned short* winh = (unsigned short*)(osg + acc_elems);
  unsigned short* winl = winh + Cz * Cz;
  unsigned short* wouth = winl + Cz * Cz;
  unsigned short* woutl = wouth + Cz * Cz;

  hipMemsetAsync(accgT, 0, (acc_elems + norm_elems) * sizeof(float), stream);

  prep_k<<<Cz, Cz, 0, stream>>>(W_in, W_out, winh, winl, wouth, woutl);
  gemm_mfma<<<dim3(Bz * Tz / 128, 2), 256, 0, stream>>>(x_q, winh, winl, b_in, tmp);
  pool_k<<<dim3(Bz * Hz, Tz / 512), 256, 0, stream>>>(tmp, W_slice, b_slice, temperature,
                                                      accgT, normg);
  attn_k<<<Bz * Hz, 256, 0, stream>>>(accgT, normg, W_q, b_q, W_k, b_k, W_v, b_v, osg);
  scatter_k<<<dim3(Bz * Hz, Tz / 512), 256, 0, stream>>>(tmp, W_slice, b_slice, temperature,
                                                         osg);
  gemm_mfma<<<dim3(Bz * Tz / 128, 2), 256, 0, stream>>>(tmp, wouth, woutl, b_out, out);
}